// Round 8
// baseline (2052.292 us; speedup 1.0000x reference)
//
#include <hip/hip_runtime.h>
#include <math.h>

#define NPTS 8192
#define PPC  1024
#define BCL  8
#define KNN  20
#define HDIM 256
#define HD2  512
#define NL   3
#define NCOMP 512
#define EDG  (NPTS*KNN)
#define QS   768   // fused qkv row stride: [a_src | a_dst | v]

typedef __bf16 bf16x8 __attribute__((ext_vector_type(8)));
typedef float f32x4 __attribute__((ext_vector_type(4)));
typedef unsigned int uint4v __attribute__((ext_vector_type(4)));
typedef unsigned short us8 __attribute__((ext_vector_type(8)));

__device__ inline unsigned short f2bf(float f) {        // RNE (weight prep)
  unsigned u = __float_as_uint(f);
  u += 0x7FFF + ((u >> 16) & 1);
  return (unsigned short)(u >> 16);
}
__device__ inline unsigned short f2bf_fast(float f) {   // round-half-up, 2 ops
  return (unsigned short)((__float_as_uint(f) + 0x8000u) >> 16);
}
__device__ inline unsigned pack2bf(float a, float b) {  // 2 floats -> packed bf16x2
#if __has_builtin(__builtin_amdgcn_cvt_pk_bf16_f32)
  auto t = __builtin_amdgcn_cvt_pk_bf16_f32(a, b);
  return __builtin_bit_cast(unsigned, t);
#else
  return ((__float_as_uint(a) + 0x8000u) >> 16) |
         ((__float_as_uint(b) + 0x8000u) & 0xFFFF0000u);
#endif
}
__device__ inline float bf2f(unsigned short u) {
  return __uint_as_float((unsigned)u << 16);
}
__device__ inline float elu(float y) { return (y > 0.f) ? y : (__expf(y) - 1.f); }

// ---------------- KNN: one WAVE per point ----------------
__global__ __launch_bounds__(256)
void knn_wave(const float* __restrict__ pos, int* __restrict__ neigh,
              float* __restrict__ rel_f) {
  __shared__ float px[PPC], py[PPC], pz[PPC];
  int tid = threadIdx.x;
  int i0 = blockIdx.x * 4;
  int base = i0 & ~(PPC - 1);
  for (int t = tid; t < PPC; t += 256) {
    px[t] = pos[(size_t)(base + t) * 3 + 0];
    py[t] = pos[(size_t)(base + t) * 3 + 1];
    pz[t] = pos[(size_t)(base + t) * 3 + 2];
  }
  __syncthreads();
  int wave = tid >> 6, lane = tid & 63;
  int i = i0 + wave;
  int il = i - base;
  float xi = px[il], yi = py[il], zi = pz[il];
  float d[16];
  #pragma unroll
  for (int q = 0; q < 16; ++q) {
    int t = lane + 64 * q;
    float dx = xi - px[t], dy = yi - py[t], dz = zi - pz[t];
    float dd = dx * dx + dy * dy + dz * dz;
    d[q] = (t == il) ? 3.4e38f : dd;
  }
  int mywin = 0;
  for (int k = 0; k < KNN; ++k) {
    float v = d[0]; int idx = lane;
    #pragma unroll
    for (int q = 1; q < 16; ++q)
      if (d[q] < v) { v = d[q]; idx = q * 64 + lane; }
    #pragma unroll
    for (int off = 1; off < 64; off <<= 1) {
      float ov = __shfl_xor(v, off, 64);
      int oi = __shfl_xor(idx, off, 64);
      if (ov < v || (ov == v && oi < idx)) { v = ov; idx = oi; }
    }
    if (lane == k) mywin = idx;
    int qwin = idx >> 6;
    bool own = (idx & 63) == lane;
    #pragma unroll
    for (int q = 0; q < 16; ++q)
      if (own && q == qwin) d[q] = 3.4e38f;
  }
  if (lane < KNN) {
    neigh[(size_t)i * KNN + lane] = base + mywin;
    size_t rb = ((size_t)i * KNN + lane) * 3;
    rel_f[rb + 0] = xi - px[mywin];
    rel_f[rb + 1] = yi - py[mywin];
    rel_f[rb + 2] = zi - pz[mywin];
  }
}

// ---------------- weight prep: fp32 [K][N] -> bf16 [N][Kpad] ----------------
__global__ __launch_bounds__(256)
void transpose_w(const float* __restrict__ W, unsigned short* __restrict__ out,
                 int K, int N, int Kpad) {
  int n = blockIdx.x;
  for (int k = threadIdx.x; k < Kpad; k += 256)
    out[(size_t)n * Kpad + k] = (k < K) ? f2bf(W[(size_t)k * N + n]) : (unsigned short)0;
}

// ---------------- weight prep: fp32 [K][N] -> packed MFMA-fragment order ----------------
__global__ __launch_bounds__(64)
void pack_w(const float* __restrict__ W, unsigned short* __restrict__ out, int N) {
  int blk = blockIdx.x;
  int NT = N / 16;
  int ks = blk / NT, nt = blk % NT;
  int lane = threadIdx.x;
  int l16 = lane & 15, quad = lane >> 4;
  int col = nt * 16 + l16;
  int krow = ks * 32 + quad * 8;
  unsigned short o[8];
  #pragma unroll
  for (int j = 0; j < 8; ++j)
    o[j] = f2bf(W[(size_t)(krow + j) * N + col]);
  *(uint4v*)&out[((size_t)blk * 64 + lane) * 8] = *(uint4v*)o;
}

__global__ __launch_bounds__(256)
void prep_pos(const float* __restrict__ pos, unsigned short* __restrict__ posb) {
  int idx = blockIdx.x * 256 + threadIdx.x;
  int m = idx >> 5, c = idx & 31;
  posb[idx] = (c < 3) ? f2bf(pos[(size_t)m * 3 + c]) : (unsigned short)0;
}

// ================= pos_nn fused (packed-global B in phase 2, barrier-free k-loop) =================
__global__ __launch_bounds__(256)
void pos_fused(const float* __restrict__ rel_f, const float* __restrict__ W1,
               const float* __restrict__ b1, const float* __restrict__ g1,
               const float* __restrict__ be1,
               const unsigned short* __restrict__ B2p, const float* __restrict__ bias2,
               const float* __restrict__ g2, const float* __restrict__ be2,
               unsigned short* __restrict__ delta_b, int edge_base) {
  __shared__ alignas(16) char smem[46464];
  unsigned short* H = (unsigned short*)smem;                  // [32][520]
  float* w1s = (float*)(smem + 33280);                        // [3][512]
  float* b1s = w1s + 1536;
  float* g1s = b1s + 512;
  float* be1s = g1s + 512;
  float* lnsum = (float*)(smem + 45568);                      // [2][32]
  float* lnsq = lnsum + 64;
  float* relS = (float*)(smem + 46080);                       // [32][3]
  int tid = threadIdx.x;
  int wave = tid >> 6, lane = tid & 63;
  int el0 = blockIdx.x * 32;
  int eg0 = edge_base + el0;
  for (int t = tid; t < 1536; t += 256) w1s[t] = W1[t];
  for (int t = tid; t < 512; t += 256) { b1s[t] = b1[t]; g1s[t] = g1[t]; be1s[t] = be1[t]; }
  if (tid < 96) relS[tid] = rel_f[(size_t)eg0 * 3 + tid];
  __syncthreads();
  // ---- phase 1: rank-3 VALU fp32; row = 8 consecutive lanes ----
  {
    int rIW = lane >> 3, sub = lane & 7;
    int row = wave * 8 + rIW;
    float r0 = relS[row * 3 + 0], r1v = relS[row * 3 + 1], r2v = relS[row * 3 + 2];
    int cb = sub * 64;
    float h[64]; float s = 0.f, sq = 0.f;
    #pragma unroll
    for (int cc = 0; cc < 16; ++cc) {
      f32x4 w0 = *(const f32x4*)&w1s[cb + cc * 4];
      f32x4 wa = *(const f32x4*)&w1s[512 + cb + cc * 4];
      f32x4 wb = *(const f32x4*)&w1s[1024 + cb + cc * 4];
      f32x4 bb = *(const f32x4*)&b1s[cb + cc * 4];
      #pragma unroll
      for (int q = 0; q < 4; ++q) {
        float hv = fmaf(r0, w0[q], fmaf(r1v, wa[q], fmaf(r2v, wb[q], bb[q])));
        h[cc * 4 + q] = hv; s += hv; sq += hv * hv;
      }
    }
    #pragma unroll
    for (int off = 1; off < 8; off <<= 1) { s += __shfl_xor(s, off, 64); sq += __shfl_xor(sq, off, 64); }
    float mean = s * (1.f / 512.f);
    float var = sq * (1.f / 512.f) - mean * mean;
    float rr = rsqrtf(var + 1e-5f);
    #pragma unroll
    for (int cc = 0; cc < 8; ++cc) {
      unsigned u[4];
      #pragma unroll
      for (int q = 0; q < 4; ++q) {
        int c0 = cb + cc * 8 + 2 * q;
        float y0 = elu((h[cc * 8 + 2 * q]     - mean) * rr * g1s[c0]     + be1s[c0]);
        float y1 = elu((h[cc * 8 + 2 * q + 1] - mean) * rr * g1s[c0 + 1] + be1s[c0 + 1]);
        u[q] = pack2bf(y0, y1);
      }
      *(uint4v*)&H[row * 520 + cb + cc * 8] = *(uint4v*)u;
    }
  }
  __syncthreads();
  // ---- phase 2: barrier-free MFMA, packed-coalesced B2 (N=256 -> NT=16) ----
  int quad = lane >> 4, l16 = lane & 15;
  int wm2 = (wave >> 1) * 16, wn2 = (wave & 1) * 128, wni = wave & 1;
  int nb2 = (wave & 1) * 8;
  f32x4 acc2[8] = {};
  for (int k0 = 0; k0 < 512; k0 += 32) {
    int ks = k0 >> 5;
    bf16x8 bvv[8];
    #pragma unroll
    for (int ni = 0; ni < 8; ++ni)
      bvv[ni] = *(const bf16x8*)(B2p + ((size_t)(ks * 16 + nb2 + ni) * 64 + lane) * 8);
    bf16x8 a2 = __builtin_bit_cast(bf16x8, *(const uint4v*)&H[(wm2 + l16) * 520 + k0 + quad * 8]);
    #pragma unroll
    for (int ni = 0; ni < 8; ++ni)
      acc2[ni] = __builtin_amdgcn_mfma_f32_16x16x32_bf16(a2, bvv[ni], acc2[ni], 0, 0, 0);
  }
  #pragma unroll
  for (int r = 0; r < 4; ++r) {
    int row = wm2 + quad * 4 + r;
    float s2 = 0.f, q2 = 0.f;
    #pragma unroll
    for (int ni = 0; ni < 8; ++ni) {
      float val = acc2[ni][r] + bias2[wn2 + ni * 16 + l16];
      acc2[ni][r] = val; s2 += val; q2 += val * val;
    }
    #pragma unroll
    for (int off = 1; off < 16; off <<= 1) { s2 += __shfl_xor(s2, off, 64); q2 += __shfl_xor(q2, off, 64); }
    if (l16 == 0) { lnsum[wni * 32 + row] = s2; lnsq[wni * 32 + row] = q2; }
  }
  __syncthreads();
  #pragma unroll
  for (int r = 0; r < 4; ++r) {
    int row = wm2 + quad * 4 + r;
    float tot = lnsum[row] + lnsum[32 + row];
    float tsq = lnsq[row] + lnsq[32 + row];
    float mean = tot * (1.f / 256.f);
    float var = tsq * (1.f / 256.f) - mean * mean;
    float rr = rsqrtf(var + 1e-5f);
    size_t ob = (size_t)(el0 + row) * 256;
    #pragma unroll
    for (int ni = 0; ni < 8; ++ni) {
      int col = wn2 + ni * 16 + l16;
      delta_b[ob + col] = f2bf_fast(elu((acc2[ni][r] - mean) * rr * g2[col] + be2[col]));
    }
  }
}

// ================= attn fused v3: low-reg phase 1 (two N-halves, deferred LN) =================
// smem: H[32][520] @0 (33280, raw then normalized) | lnsum/lnsq @33280 (512) | iS/jS @33792 (256)
__global__ __launch_bounds__(256)
void attn_fused(const unsigned short* __restrict__ qkv,
                const unsigned short* __restrict__ delta_b,
                const int* __restrict__ neigh,
                const unsigned short* __restrict__ B1p, const float* __restrict__ bias1,
                const float* __restrict__ g1, const float* __restrict__ be1,
                const unsigned short* __restrict__ B2p, const float* __restrict__ bias2,
                const float* __restrict__ g2, const float* __restrict__ be2,
                unsigned short* __restrict__ alpha_b, int edge_base) {
  __shared__ alignas(16) char smem[34304];
  unsigned short* H = (unsigned short*)smem;                   // [32][520]
  float* lnsum = (float*)(smem + 33280);                       // [2][32]
  float* lnsq  = lnsum + 64;
  int* iS = (int*)(smem + 33792);
  int* jS = iS + 32;
  int tid = threadIdx.x;
  int wave = tid >> 6, lane = tid & 63;
  int quad = lane >> 4, l16 = lane & 15;
  int el0 = blockIdx.x * 32;
  int eg0 = edge_base + el0;
  if (tid < 32) { iS[tid] = (eg0 + tid) / KNN; jS[tid] = neigh[eg0 + tid]; }
  __syncthreads();
  int wm1 = (wave >> 1) * 16, wni = wave & 1;
  // ---- gather this lane's A row (t = a_dst[i] - a_src[j] + delta[e]) into registers ----
  us8 areg[8];
  {
    int r = wm1 + l16;
    int i = iS[r], j = jS[r], e = el0 + r;
    const unsigned short* pdp = qkv + (size_t)i * QS + 256;
    const unsigned short* psp = qkv + (size_t)j * QS;
    const unsigned short* plp = delta_b + (size_t)e * 256;
    #pragma unroll
    for (int ks = 0; ks < 8; ++ks) {
      int c = ks * 32 + quad * 8;
      us8 pd = *(const us8*)(pdp + c);
      us8 ps = *(const us8*)(psp + c);
      us8 pl = *(const us8*)(plp + c);
      unsigned u[4];
      #pragma unroll
      for (int q = 0; q < 4; ++q)
        u[q] = pack2bf(bf2f(pd[2*q])   - bf2f(ps[2*q])   + bf2f(pl[2*q]),
                       bf2f(pd[2*q+1]) - bf2f(ps[2*q+1]) + bf2f(pl[2*q+1]));
      areg[ks] = __builtin_bit_cast(us8, *(uint4v*)u);
    }
  }
  // ---- phase 1: two sequential N-halves of 256 cols, raw output + deferred LN ----
  float sAcc[4] = {0.f, 0.f, 0.f, 0.f}, qAcc[4] = {0.f, 0.f, 0.f, 0.f};
  for (int half = 0; half < 2; ++half) {
    int nb = half * 16 + wni * 8;        // n-tile base (of 32 tiles of 16 cols)
    int cb = nb * 16;                    // col base
    f32x4 acc[8] = {};
    #pragma unroll
    for (int ks = 0; ks < 8; ++ks) {
      bf16x8 bvv[8];
      #pragma unroll
      for (int ni = 0; ni < 8; ++ni)
        bvv[ni] = *(const bf16x8*)(B1p + ((size_t)(ks * 32 + nb + ni) * 64 + lane) * 8);
      bf16x8 a1 = __builtin_bit_cast(bf16x8, areg[ks]);
      #pragma unroll
      for (int ni = 0; ni < 8; ++ni)
        acc[ni] = __builtin_amdgcn_mfma_f32_16x16x32_bf16(a1, bvv[ni], acc[ni], 0, 0, 0);
    }
    #pragma unroll
    for (int r = 0; r < 4; ++r) {
      int row = wm1 + quad * 4 + r;
      #pragma unroll
      for (int ni = 0; ni < 8; ++ni) {
        float val = acc[ni][r] + bias1[cb + ni * 16 + l16];
        sAcc[r] += val; qAcc[r] += val * val;
        H[row * 520 + cb + ni * 16 + l16] = f2bf_fast(val);
      }
    }
  }
  // ---- LN stats: butterfly over 16 lanes, combine across wni via LDS ----
  #pragma unroll
  for (int r = 0; r < 4; ++r) {
    float s = sAcc[r], sq = qAcc[r];
    #pragma unroll
    for (int off = 1; off < 16; off <<= 1) { s += __shfl_xor(s, off, 64); sq += __shfl_xor(sq, off, 64); }
    int row = wm1 + quad * 4 + r;
    if (l16 == 0) { lnsum[wni * 32 + row] = s; lnsq[wni * 32 + row] = sq; }
  }
  __syncthreads();
  // ---- normalization pass: 256 threads over 32 rows x 512 cols, in place ----
  {
    int row = tid >> 3;
    int c0 = (tid & 7) * 64;
    float mean = (lnsum[row] + lnsum[32 + row]) * (1.f / 512.f);
    float var = (lnsq[row] + lnsq[32 + row]) * (1.f / 512.f) - mean * mean;
    float rr = rsqrtf(var + 1e-5f);
    #pragma unroll
    for (int c8 = 0; c8 < 8; ++c8) {
      int c = c0 + c8 * 8;
      us8 hv = *(const us8*)&H[row * 520 + c];
      unsigned u[4];
      #pragma unroll
      for (int q = 0; q < 4; ++q) {
        float y0 = elu((bf2f(hv[2*q])   - mean) * rr * g1[c + 2*q]   + be1[c + 2*q]);
        float y1 = elu((bf2f(hv[2*q+1]) - mean) * rr * g1[c + 2*q+1] + be1[c + 2*q+1]);
        u[q] = pack2bf(y0, y1);
      }
      *(uint4v*)&H[row * 520 + c] = *(uint4v*)u;
    }
  }
  __syncthreads();
  // ---- phase 2: K=512, barrier-free, packed B2 (N=256 -> NT=16) ----
  int wm2 = (wave >> 1) * 16, wn2 = (wave & 1) * 128;
  int nb2 = (wave & 1) * 8;
  f32x4 acc2[8] = {};
  for (int k0 = 0; k0 < 512; k0 += 32) {
    int ks = k0 >> 5;
    bf16x8 bvv[8];
    #pragma unroll
    for (int ni = 0; ni < 8; ++ni)
      bvv[ni] = *(const bf16x8*)(B2p + ((size_t)(ks * 16 + nb2 + ni) * 64 + lane) * 8);
    bf16x8 a2 = __builtin_bit_cast(bf16x8, *(const uint4v*)&H[(wm2 + l16) * 520 + k0 + quad * 8]);
    #pragma unroll
    for (int ni = 0; ni < 8; ++ni)
      acc2[ni] = __builtin_amdgcn_mfma_f32_16x16x32_bf16(a2, bvv[ni], acc2[ni], 0, 0, 0);
  }
  #pragma unroll
  for (int r = 0; r < 4; ++r) {
    int row = wm2 + quad * 4 + r;
    float s2 = 0.f, q2 = 0.f;
    #pragma unroll
    for (int ni = 0; ni < 8; ++ni) {
      float val = acc2[ni][r] + bias2[wn2 + ni * 16 + l16];
      acc2[ni][r] = val; s2 += val; q2 += val * val;
    }
    #pragma unroll
    for (int off = 1; off < 16; off <<= 1) { s2 += __shfl_xor(s2, off, 64); q2 += __shfl_xor(q2, off, 64); }
    if (l16 == 0) { lnsum[wni * 32 + row] = s2; lnsq[wni * 32 + row] = q2; }
  }
  __syncthreads();
  #pragma unroll
  for (int r = 0; r < 4; ++r) {
    int row = wm2 + quad * 4 + r;
    float tot = lnsum[row] + lnsum[32 + row];
    float tsq = lnsq[row] + lnsq[32 + row];
    float mean = tot * (1.f / 256.f);
    float var = tsq * (1.f / 256.f) - mean * mean;
    float rr = rsqrtf(var + 1e-5f);
    size_t ob = (size_t)(el0 + row) * 256;
    #pragma unroll
    for (int ni = 0; ni < 8; ++ni) {
      int col = wn2 + ni * 16 + l16;
      alpha_b[ob + col] = f2bf_fast(elu((acc2[ni][r] - mean) * rr * g2[col] + be2[col]));
    }
  }
}

// ---------------- plain bf16 MFMA GEMM ----------------
#define APAD 40
__global__ __launch_bounds__(256)
void gemm_mfma(const unsigned short* __restrict__ A, const unsigned short* __restrict__ Bt,
               const float* __restrict__ bias, float* __restrict__ Cf,
               unsigned short* __restrict__ Cb, int M, int Nn, int Kk) {
  __shared__ alignas(16) unsigned short As[128 * APAD];
  __shared__ alignas(16) unsigned short Bs[128 * APAD];
  int tid = threadIdx.x;
  int wave = tid >> 6, lane = tid & 63;
  int quad = lane >> 4, l16 = lane & 15;
  int wm = (wave >> 1) * 64, wn = (wave & 1) * 64;
  int m0 = blockIdx.y * 128, n0 = blockIdx.x * 128;
  f32x4 acc[4][4] = {};
  int srow = tid >> 2;
  int scol = (tid & 3) * 8;
  for (int k0 = 0; k0 < Kk; k0 += 32) {
    #pragma unroll
    for (int h = 0; h < 2; ++h) {
      int r = srow + h * 64;
      int gm = m0 + r;
      uint4v va = {0, 0, 0, 0};
      if (gm < M) va = *(const uint4v*)(A + (size_t)gm * Kk + k0 + scol);
      *(uint4v*)(&As[r * APAD + scol]) = va;
      int gn = n0 + r;
      uint4v vb = *(const uint4v*)(Bt + (size_t)gn * Kk + k0 + scol);
      *(uint4v*)(&Bs[r * APAD + scol]) = vb;
    }
    __syncthreads();
    bf16x8 af[4], bfr[4];
    #pragma unroll
    for (int mi = 0; mi < 4; ++mi)
      af[mi] = __builtin_bit_cast(bf16x8, *(const uint4v*)(&As[(wm + mi * 16 + l16) * APAD + quad * 8]));
    #pragma unroll
    for (int ni = 0; ni < 4; ++ni)
      bfr[ni] = __builtin_bit_cast(bf16x8, *(const uint4v*)(&Bs[(wn + ni * 16 + l16) * APAD + quad * 8]));
    #pragma unroll
    for (int mi = 0; mi < 4; ++mi)
      #pragma unroll
      for (int ni = 0; ni < 4; ++ni)
        acc[mi][ni] = __builtin_amdgcn_mfma_f32_16x16x32_bf16(af[mi], bfr[ni], acc[mi][ni], 0, 0, 0);
    __syncthreads();
  }
  float bvs[4]; int gns[4];
  #pragma unroll
  for (int ni = 0; ni < 4; ++ni) {
    gns[ni] = n0 + wn + ni * 16 + l16;
    bvs[ni] = bias ? bias[gns[ni]] : 0.f;
  }
  #pragma unroll
  for (int mi = 0; mi < 4; ++mi) {
    #pragma unroll
    for (int r = 0; r < 4; ++r) {
      int gm = m0 + wm + mi * 16 + quad * 4 + r;
      if (gm >= M) continue;
      #pragma unroll
      for (int ni = 0; ni < 4; ++ni) {
        float val = acc[mi][ni][r] + bvs[ni];
        if (Cf) Cf[(size_t)gm * Nn + gns[ni]] = val;
        if (Cb) Cb[(size_t)gm * Nn + gns[ni]] = f2bf_fast(val);
      }
    }
  }
}

// ---------------- fp32 tiled GEMM (head only, M=8) ----------------
#define BM0 64
#define BN0 64
#define BK0 16
__global__ __launch_bounds__(256)
void gemm_bias(const float* __restrict__ A, const float* __restrict__ Bw,
               const float* __restrict__ bias, float* __restrict__ C,
               int M, int Nn, int Kk) {
  __shared__ float Asm[BK0][BM0 + 1];
  __shared__ float Bsm[BK0][BN0 + 1];
  int bm = blockIdx.y * BM0, bn = blockIdx.x * BN0;
  int tid = threadIdx.x;
  int tx = tid & 15, ty = tid >> 4;
  float acc[4][4] = {{0.f}};
  for (int k0 = 0; k0 < Kk; k0 += BK0) {
    #pragma unroll
    for (int ii = 0; ii < 4; ++ii) {
      int e = tid + ii * 256;
      int m = e >> 4, k = e & 15;
      int gm = bm + m, gk = k0 + k;
      Asm[k][m] = (gm < M && gk < Kk) ? A[(size_t)gm * Kk + gk] : 0.f;
    }
    #pragma unroll
    for (int ii = 0; ii < 4; ++ii) {
      int e = tid + ii * 256;
      int k = e >> 6, n = e & 63;
      int gk = k0 + k, gn = bn + n;
      Bsm[k][n] = (gk < Kk && gn < Nn) ? Bw[(size_t)gk * Nn + gn] : 0.f;
    }
    __syncthreads();
    #pragma unroll
    for (int kk = 0; kk < BK0; ++kk) {
      float a[4], b[4];
      #pragma unroll
      for (int ii = 0; ii < 4; ++ii) a[ii] = Asm[kk][ty * 4 + ii];
      #pragma unroll
      for (int jj = 0; jj < 4; ++jj) b[jj] = Bsm[kk][tx * 4 + jj];
      #pragma unroll
      for (int ii = 0; ii < 4; ++ii)
        #pragma unroll
        for (int jj = 0; jj < 4; ++jj)
          acc[ii][jj] += a[ii] * b[jj];
    }
    __syncthreads();
  }
  #pragma unroll
  for (int ii = 0; ii < 4; ++ii) {
    int gm = bm + ty * 4 + ii;
    if (gm >= M) continue;
    #pragma unroll
    for (int jj = 0; jj < 4; ++jj) {
      int gn = bn + tx * 4 + jj;
      if (gn >= Nn) continue;
      float vv = acc[ii][jj];
      if (bias) vv += bias[gn];
      C[(size_t)gm * Nn + gn] = vv;
    }
  }
}

// ---------------- LayerNorm + ELU (tail & head) ----------------
__global__ __launch_bounds__(256)
void ln_elu_kernel(const float* __restrict__ in, float* __restrict__ outf,
                   unsigned short* __restrict__ outb,
                   const float* __restrict__ g, const float* __restrict__ bb,
                   int Cn, int do_elu) {
  __shared__ float sdata[4];
  size_t row = blockIdx.x;
  const float* x = in + row * Cn;
  int tid = threadIdx.x;
  float v0 = x[tid];
  float v1 = (Cn == 512) ? x[tid + 256] : 0.f;
  float s = v0 + v1;
  #pragma unroll
  for (int off = 32; off > 0; off >>= 1) s += __shfl_xor(s, off, 64);
  if ((tid & 63) == 0) sdata[tid >> 6] = s;
  __syncthreads();
  float mean = (sdata[0] + sdata[1] + sdata[2] + sdata[3]) / (float)Cn;
  float d0 = v0 - mean;
  float d1 = (Cn == 512) ? (v1 - mean) : 0.f;
  float sq = d0 * d0 + d1 * d1;
  __syncthreads();
  #pragma unroll
  for (int off = 32; off > 0; off >>= 1) sq += __shfl_xor(sq, off, 64);
  if ((tid & 63) == 0) sdata[tid >> 6] = sq;
  __syncthreads();
  float var = (sdata[0] + sdata[1] + sdata[2] + sdata[3]) / (float)Cn;
  float r = rsqrtf(var + 1e-5f);
  float y0 = d0 * r * g[tid] + bb[tid];
  if (do_elu) y0 = elu(y0);
  if (outf) outf[row * Cn + tid] = y0;
  if (outb) outb[row * Cn + tid] = f2bf_fast(y0);
  if (Cn == 512) {
    float y1 = d1 * r * g[tid + 256] + bb[tid + 256];
    if (do_elu) y1 = elu(y1);
    if (outf) outf[row * Cn + tid + 256] = y1;
    if (outb) outb[row * Cn + tid + 256] = f2bf_fast(y1);
  }
}

// ---------------- per-channel softmax over K + weighted aggregation ----------------
__global__ __launch_bounds__(256)
void softmax_agg(const unsigned short* __restrict__ alpha_b,
                 const unsigned short* __restrict__ delta_b,
                 const unsigned short* __restrict__ qkv,
                 const int* __restrict__ neigh,
                 float* __restrict__ agg, int node0) {
  int nl = blockIdx.x;
  int c = threadIdx.x;
  int i = node0 + nl;
  float av[KNN];
  float mx = -3.4e38f;
  #pragma unroll
  for (int k = 0; k < KNN; ++k) {
    av[k] = bf2f(alpha_b[((size_t)nl * KNN + k) * HDIM + c]);
    mx = fmaxf(mx, av[k]);
  }
  float ssum = 0.f;
  #pragma unroll
  for (int k = 0; k < KNN; ++k) { av[k] = __expf(av[k] - mx); ssum += av[k]; }
  float inv = 1.f / ssum;
  float acc = 0.f;
  #pragma unroll
  for (int k = 0; k < KNN; ++k) {
    int j = neigh[(size_t)i * KNN + k];
    acc += av[k] * inv * (bf2f(qkv[(size_t)j * QS + 512 + c]) +
                          bf2f(delta_b[((size_t)nl * KNN + k) * HDIM + c]));
  }
  agg[(size_t)i * HDIM + c] = acc;
}

// ---------------- x += res_alpha[l] * h ; xb = bf16(x) ----------------
__global__ __launch_bounds__(256)
void axpy_res(float* __restrict__ x, unsigned short* __restrict__ xb,
              const float* __restrict__ h, const float* __restrict__ alpha, int l) {
  size_t idx = (size_t)blockIdx.x * 256 + threadIdx.x;
  float nv = x[idx] + alpha[l] * h[idx];
  x[idx] = nv;
  xb[idx] = f2bf_fast(nv);
}

// ---------------- global max pool, two-stage ----------------
__global__ __launch_bounds__(256)
void seg_max_p(const float* __restrict__ h, float* __restrict__ part) {
  int blk = blockIdx.x;
  int b = blk >> 4, ch = blk & 15;
  int c = threadIdx.x;
  const float* base = h + ((size_t)b * PPC + (size_t)ch * 64) * HDIM;
  float m = -3.4e38f;
  for (int p = 0; p < 64; ++p)
    m = fmaxf(m, base[(size_t)p * HDIM + c]);
  part[(size_t)blk * HDIM + c] = m;
}
__global__ __launch_bounds__(256)
void seg_max_f(const float* __restrict__ part, float* __restrict__ pooled) {
  int b = blockIdx.x;
  int c = threadIdx.x;
  float m = -3.4e38f;
  for (int k = 0; k < 16; ++k)
    m = fmaxf(m, part[(size_t)(b * 16 + k) * HDIM + c]);
  pooled[(size_t)b * HDIM + c] = m;
}

extern "C" void kernel_launch(void* const* d_in, const int* in_sizes, int n_in,
                              void* d_out, int out_size, void* d_ws, size_t ws_size,
                              hipStream_t stream) {
  const float* pos       = (const float*)d_in[0];
  const float* ffm_W     = (const float*)d_in[2];
  const float* ffm_b     = (const float*)d_in[3];
  const float* lin_W     = (const float*)d_in[4];
  const float* src_W     = (const float*)d_in[5];
  const float* dst_W     = (const float*)d_in[6];
  const float* pos1_W    = (const float*)d_in[7];
  const float* pos1_b    = (const float*)d_in[8];
  const float* pos_ln1_g = (const float*)d_in[9];
  const float* pos_ln1_b = (const float*)d_in[10];
  const float* pos2_W    = (const float*)d_in[11];
  const float* pos2_b    = (const float*)d_in[12];
  const float* pos_ln2_g = (const float*)d_in[13];
  const float* pos_ln2_b = (const float*)d_in[14];
  const float* att1_W    = (const float*)d_in[15];
  const float* att1_b    = (const float*)d_in[16];
  const float* att_ln1_g = (const float*)d_in[17];
  const float* att_ln1_b = (const float*)d_in[18];
  const float* att2_W    = (const float*)d_in[19];
  const float* att2_b    = (const float*)d_in[20];
  const float* att_ln2_g = (const float*)d_in[21];
  const float* att_ln2_b = (const float*)d_in[22];
  const float* blk_ln_g  = (const float*)d_in[23];
  const float* blk_ln_b  = (const float*)d_in[24];
  const float* blk_W     = (const float*)d_in[25];
  const float* blk_b     = (const float*)d_in[26];
  const float* res_alpha = (const float*)d_in[27];
  const float* r1_W = (const float*)d_in[28]; const float* r1_b = (const float*)d_in[29];
  const float* r2_W = (const float*)d_in[30]; const float* r2_b = (const float*)d_in[31];
  const float* r2_ln_g = (const float*)d_in[32]; const float* r2_ln_b = (const float*)d_in[33];
  const float* r3_W = (const float*)d_in[34]; const float* r3_b = (const float*)d_in[35];
  const float* r3_ln_g = (const float*)d_in[36]; const float* r3_ln_b = (const float*)d_in[37];
  const float* r4_W = (const float*)d_in[38]; const float* r4_b = (const float*)d_in[39];
  float* out = (float*)d_out;

  // ---- workspace carve-up ----
  char* wsp = (char*)d_ws;
  auto alloc = [&](size_t bytes) -> void* {
    void* p = (void*)wsp;
    wsp += (bytes + 255) & ~(size_t)255;
    return p;
  };
  int*            neigh   = (int*)alloc(EDG * sizeof(int));
  float*          rel_f   = (float*)alloc((size_t)EDG * 3 * 4);
  unsigned short* posb    = (unsigned short*)alloc((size_t)NPTS * 32 * 2);
  float*          x       = (float*)alloc((size_t)NPTS * HDIM * 4);
  unsigned short* xb      = (unsigned short*)alloc((size_t)NPTS * HDIM * 2);
  unsigned short* xln_b   = (unsigned short*)alloc((size_t)NPTS * HDIM * 2);
  unsigned short* qkv     = (unsigned short*)alloc((size_t)NPTS * QS * 2);
  float*          agg     = (float*)alloc((size_t)NPTS * HDIM * 4);
  float*          segp    = (float*)alloc((size_t)128 * HDIM * 4);
  float*          pooled  = (float*)alloc((size_t)BCL * HDIM * 4);
  float*          hh      = (float*)alloc((size_t)BCL * HDIM * 4);
  unsigned short* ffmt = (unsigned short*)alloc((size_t)HDIM * 32 * 2);
  unsigned short* r1t  = (unsigned short*)alloc((size_t)HDIM * HDIM * 2);
  unsigned short *qkvt[NL], *blkt[NL];
  unsigned short *pos2p[NL], *att1p[NL], *att2p[NL];
  for (int l = 0; l < NL; ++l) {
    qkvt[l]  = (unsigned short*)alloc((size_t)QS * HDIM * 2);
    blkt[l]  = (unsigned short*)alloc((size_t)HDIM * HDIM * 2);
    pos2p[l] = (unsigned short*)alloc((size_t)HDIM * HD2 * 2);   // packed
    att1p[l] = (unsigned short*)alloc((size_t)HD2 * HDIM * 2);   // packed
    att2p[l] = (unsigned short*)alloc((size_t)HDIM * HD2 * 2);   // packed
  }
  // chunked edge buffers: delta + alpha (bf16)
  size_t used = (size_t)(wsp - (char*)d_ws);
  size_t avail = (ws_size > used) ? (ws_size - used) : 0;
  size_t per_node = (size_t)KNN * (HDIM * 2 * 2) + 1024;
  int Nc = (int)(avail / per_node);
  if (Nc > NPTS) Nc = NPTS;
  Nc &= ~15;
  if (Nc < 16) Nc = 16;
  unsigned short* delta_b = (unsigned short*)alloc((size_t)Nc * KNN * HDIM * 2);
  unsigned short* alpha_b = (unsigned short*)alloc((size_t)Nc * KNN * HDIM * 2);

  auto mgemm = [&](const unsigned short* A, const unsigned short* Bt, const float* bias,
                   float* Cf, unsigned short* Cb, int M, int Nn, int Kk) {
    dim3 g(Nn / 128, (M + 127) / 128);
    gemm_mfma<<<g, dim3(256), 0, stream>>>(A, Bt, bias, Cf, Cb, M, Nn, Kk);
  };
  auto fgemm = [&](const float* A, const float* Bw, const float* bias, float* Cp,
                   int M, int Nn, int Kk) {
    dim3 g((Nn + BN0 - 1) / BN0, (M + BM0 - 1) / BM0);
    gemm_bias<<<g, dim3(256), 0, stream>>>(A, Bw, bias, Cp, M, Nn, Kk);
  };

  // ---- weight prep ----
  transpose_w<<<HDIM, 256, 0, stream>>>(ffm_W, ffmt, 3, HDIM, 32);
  transpose_w<<<HDIM, 256, 0, stream>>>(r1_W, r1t, HDIM, HDIM, HDIM);
  for (int l = 0; l < NL; ++l) {
    transpose_w<<<HDIM, 256, 0, stream>>>(src_W + (size_t)l * HDIM * HDIM, qkvt[l], HDIM, HDIM, HDIM);
    transpose_w<<<HDIM, 256, 0, stream>>>(dst_W + (size_t)l * HDIM * HDIM, qkvt[l] + 256 * 256, HDIM, HDIM, HDIM);
    transpose_w<<<HDIM, 256, 0, stream>>>(lin_W + (size_t)l * HDIM * HDIM, qkvt[l] + 512 * 256, HDIM, HDIM, HDIM);
    transpose_w<<<HDIM, 256, 0, stream>>>(blk_W + (size_t)l * HDIM * HDIM, blkt[l], HDIM, HDIM, HDIM);
    pack_w<<<(HD2 / 32) * (HDIM / 16), 64, 0, stream>>>(pos2_W + (size_t)l * HD2 * HDIM, pos2p[l], HDIM);
    pack_w<<<(HDIM / 32) * (HD2 / 16), 64, 0, stream>>>(att1_W + (size_t)l * HDIM * HD2, att1p[l], HD2);
    pack_w<<<(HD2 / 32) * (HDIM / 16), 64, 0, stream>>>(att2_W + (size_t)l * HD2 * HDIM, att2p[l], HDIM);
  }

  // ---- graph + stem ----
  knn_wave<<<NPTS / 4, 256, 0, stream>>>(pos, neigh, rel_f);
  prep_pos<<<NPTS * 32 / 256, 256, 0, stream>>>(pos, posb);
  mgemm(posb, ffmt, ffm_b, x, xb, NPTS, HDIM, 32);

  // ---- transformer layers ----
  for (int l = 0; l < NL; ++l) {
    mgemm(xb, qkvt[l], nullptr, nullptr, qkv, NPTS, QS, HDIM);   // [a_src|a_dst|v]

    for (int n0 = 0; n0 < NPTS; n0 += Nc) {
      int nc = (Nc < NPTS - n0) ? Nc : (NPTS - n0);
      int ec = nc * KNN;
      pos_fused<<<ec / 32, 256, 0, stream>>>(
          rel_f, pos1_W + (size_t)l * 3 * HD2, pos1_b + (size_t)l * HD2,
          pos_ln1_g + (size_t)l * HD2, pos_ln1_b + (size_t)l * HD2,
          pos2p[l], pos2_b + (size_t)l * HDIM,
          pos_ln2_g + (size_t)l * HDIM, pos_ln2_b + (size_t)l * HDIM,
          delta_b, n0 * KNN);
      attn_fused<<<ec / 32, 256, 0, stream>>>(
          qkv, delta_b, neigh,
          att1p[l], att1_b + (size_t)l * HD2,
          att_ln1_g + (size_t)l * HD2, att_ln1_b + (size_t)l * HD2,
          att2p[l], att2_b + (size_t)l * HDIM,
          att_ln2_g + (size_t)l * HDIM, att_ln2_b + (size_t)l * HDIM,
          alpha_b, n0 * KNN);
      softmax_agg<<<nc, 256, 0, stream>>>(alpha_b, delta_b, qkv, neigh, agg, n0);
    }
    ln_elu_kernel<<<NPTS, 256, 0, stream>>>(agg, nullptr, xln_b,
                                            blk_ln_g + (size_t)l * HDIM, blk_ln_b + (size_t)l * HDIM, HDIM, 1);
    mgemm(xln_b, blkt[l], blk_b + (size_t)l * HDIM, agg, nullptr, NPTS, HDIM, HDIM);
    axpy_res<<<(NPTS * HDIM) / 256, 256, 0, stream>>>(x, xb, agg, res_alpha, l);
  }

  // ---- regression head ----
  mgemm(xb, r1t, r1_b, agg, nullptr, NPTS, HDIM, HDIM);
  seg_max_p<<<128, 256, 0, stream>>>(agg, segp);
  seg_max_f<<<BCL, 256, 0, stream>>>(segp, pooled);
  fgemm(pooled, r2_W, r2_b, hh, BCL, HDIM, HDIM);
  ln_elu_kernel<<<BCL, 256, 0, stream>>>(hh, hh, nullptr, r2_ln_g, r2_ln_b, HDIM, 1);
  fgemm(hh, r3_W, r3_b, pooled, BCL, HDIM, HDIM);
  ln_elu_kernel<<<BCL, 256, 0, stream>>>(pooled, pooled, nullptr, r3_ln_g, r3_ln_b, HDIM, 1);
  fgemm(pooled, r4_W, r4_b, out, BCL, NCOMP, HDIM);
}

// Round 9
// 1877.251 us; speedup vs baseline: 1.0932x; 1.0932x over previous
//
#include <hip/hip_runtime.h>
#include <math.h>

#define NPTS 8192
#define PPC  1024
#define BCL  8
#define KNN  20
#define HDIM 256
#define HD2  512
#define NL   3
#define NCOMP 512
#define EDG  (NPTS*KNN)
#define QS   768   // fused qkv row stride: [a_src | a_dst | v]

typedef __bf16 bf16x8 __attribute__((ext_vector_type(8)));
typedef float f32x4 __attribute__((ext_vector_type(4)));
typedef unsigned int uint4v __attribute__((ext_vector_type(4)));
typedef unsigned short us8 __attribute__((ext_vector_type(8)));

__device__ inline unsigned short f2bf(float f) {        // RNE (weight prep)
  unsigned u = __float_as_uint(f);
  u += 0x7FFF + ((u >> 16) & 1);
  return (unsigned short)(u >> 16);
}
__device__ inline unsigned short f2bf_fast(float f) {   // round-half-up, 2 ops
  return (unsigned short)((__float_as_uint(f) + 0x8000u) >> 16);
}
__device__ inline unsigned pack2bf(float a, float b) {  // 2 floats -> packed bf16x2
  return ((__float_as_uint(a) + 0x8000u) >> 16) |
         ((__float_as_uint(b) + 0x8000u) & 0xFFFF0000u);
}
__device__ inline float bf2f(unsigned short u) {
  return __uint_as_float((unsigned)u << 16);
}
__device__ inline float elu(float y) { return (y > 0.f) ? y : (__expf(y) - 1.f); }

// ---------------- KNN: one WAVE per point ----------------
__global__ __launch_bounds__(256)
void knn_wave(const float* __restrict__ pos, int* __restrict__ neigh,
              float* __restrict__ rel_f) {
  __shared__ float px[PPC], py[PPC], pz[PPC];
  int tid = threadIdx.x;
  int i0 = blockIdx.x * 4;
  int base = i0 & ~(PPC - 1);
  for (int t = tid; t < PPC; t += 256) {
    px[t] = pos[(size_t)(base + t) * 3 + 0];
    py[t] = pos[(size_t)(base + t) * 3 + 1];
    pz[t] = pos[(size_t)(base + t) * 3 + 2];
  }
  __syncthreads();
  int wave = tid >> 6, lane = tid & 63;
  int i = i0 + wave;
  int il = i - base;
  float xi = px[il], yi = py[il], zi = pz[il];
  float d[16];
  #pragma unroll
  for (int q = 0; q < 16; ++q) {
    int t = lane + 64 * q;
    float dx = xi - px[t], dy = yi - py[t], dz = zi - pz[t];
    float dd = dx * dx + dy * dy + dz * dz;
    d[q] = (t == il) ? 3.4e38f : dd;
  }
  int mywin = 0;
  for (int k = 0; k < KNN; ++k) {
    float v = d[0]; int idx = lane;
    #pragma unroll
    for (int q = 1; q < 16; ++q)
      if (d[q] < v) { v = d[q]; idx = q * 64 + lane; }
    #pragma unroll
    for (int off = 1; off < 64; off <<= 1) {
      float ov = __shfl_xor(v, off, 64);
      int oi = __shfl_xor(idx, off, 64);
      if (ov < v || (ov == v && oi < idx)) { v = ov; idx = oi; }
    }
    if (lane == k) mywin = idx;
    int qwin = idx >> 6;
    bool own = (idx & 63) == lane;
    #pragma unroll
    for (int q = 0; q < 16; ++q)
      if (own && q == qwin) d[q] = 3.4e38f;
  }
  if (lane < KNN) {
    neigh[(size_t)i * KNN + lane] = base + mywin;
    size_t rb = ((size_t)i * KNN + lane) * 3;
    rel_f[rb + 0] = xi - px[mywin];
    rel_f[rb + 1] = yi - py[mywin];
    rel_f[rb + 2] = zi - pz[mywin];
  }
}

// ---------------- weight prep: fp32 [K][N] -> bf16 [N][Kpad] ----------------
__global__ __launch_bounds__(256)
void transpose_w(const float* __restrict__ W, unsigned short* __restrict__ out,
                 int K, int N, int Kpad) {
  int n = blockIdx.x;
  for (int k = threadIdx.x; k < Kpad; k += 256)
    out[(size_t)n * Kpad + k] = (k < K) ? f2bf(W[(size_t)k * N + n]) : (unsigned short)0;
}

// ---------------- weight prep: fp32 [K][N] -> packed MFMA-fragment order ----------------
// chunk c = ks*(N/16) + nt : 64 lanes x 8 ushorts; lane(l16,quad), j ->
//   B[n = nt*16 + l16][k = ks*32 + quad*8 + j]
__global__ __launch_bounds__(64)
void pack_w(const float* __restrict__ W, unsigned short* __restrict__ out, int N) {
  int blk = blockIdx.x;
  int NT = N / 16;
  int ks = blk / NT, nt = blk % NT;
  int lane = threadIdx.x;
  int l16 = lane & 15, quad = lane >> 4;
  int col = nt * 16 + l16;
  int krow = ks * 32 + quad * 8;
  unsigned short o[8];
  #pragma unroll
  for (int j = 0; j < 8; ++j)
    o[j] = f2bf(W[(size_t)(krow + j) * N + col]);
  *(uint4v*)&out[((size_t)blk * 64 + lane) * 8] = *(uint4v*)o;
}

__global__ __launch_bounds__(256)
void prep_pos(const float* __restrict__ pos, unsigned short* __restrict__ posb) {
  int idx = blockIdx.x * 256 + threadIdx.x;
  int m = idx >> 5, c = idx & 31;
  posb[idx] = (c < 3) ? f2bf(pos[(size_t)m * 3 + c]) : (unsigned short)0;
}

// ================= pos_nn fused: phase2 = Mt=2 x Nt=4 (wave owns n-quarter) =================
__global__ __launch_bounds__(256)
void pos_fused(const float* __restrict__ rel_f, const float* __restrict__ W1,
               const float* __restrict__ b1, const float* __restrict__ g1,
               const float* __restrict__ be1,
               const unsigned short* __restrict__ B2p, const float* __restrict__ bias2,
               const float* __restrict__ g2, const float* __restrict__ be2,
               unsigned short* __restrict__ delta_b, int edge_base) {
  __shared__ alignas(16) char smem[46976];
  unsigned short* H = (unsigned short*)smem;                  // [32][520]
  float* w1s = (float*)(smem + 33280);                        // [3][512]
  float* b1s = w1s + 1536;
  float* g1s = b1s + 512;
  float* be1s = g1s + 512;
  float* lnsum = (float*)(smem + 45568);                      // [4][32]
  float* lnsq  = (float*)(smem + 46080);                      // [4][32]
  float* relS  = (float*)(smem + 46592);                      // [32][3]
  int tid = threadIdx.x;
  int wave = tid >> 6, lane = tid & 63;
  int el0 = blockIdx.x * 32;
  int eg0 = edge_base + el0;
  for (int t = tid; t < 1536; t += 256) w1s[t] = W1[t];
  for (int t = tid; t < 512; t += 256) { b1s[t] = b1[t]; g1s[t] = g1[t]; be1s[t] = be1[t]; }
  if (tid < 96) relS[tid] = rel_f[(size_t)eg0 * 3 + tid];
  __syncthreads();
  // ---- phase 1: rank-3 VALU fp32; row = 8 consecutive lanes ----
  {
    int rIW = lane >> 3, sub = lane & 7;
    int row = wave * 8 + rIW;
    float r0 = relS[row * 3 + 0], r1v = relS[row * 3 + 1], r2v = relS[row * 3 + 2];
    int cb = sub * 64;
    float h[64]; float s = 0.f, sq = 0.f;
    #pragma unroll
    for (int cc = 0; cc < 16; ++cc) {
      f32x4 w0 = *(const f32x4*)&w1s[cb + cc * 4];
      f32x4 wa = *(const f32x4*)&w1s[512 + cb + cc * 4];
      f32x4 wb = *(const f32x4*)&w1s[1024 + cb + cc * 4];
      f32x4 bb = *(const f32x4*)&b1s[cb + cc * 4];
      #pragma unroll
      for (int q = 0; q < 4; ++q) {
        float hv = fmaf(r0, w0[q], fmaf(r1v, wa[q], fmaf(r2v, wb[q], bb[q])));
        h[cc * 4 + q] = hv; s += hv; sq += hv * hv;
      }
    }
    #pragma unroll
    for (int off = 1; off < 8; off <<= 1) { s += __shfl_xor(s, off, 64); sq += __shfl_xor(sq, off, 64); }
    float mean = s * (1.f / 512.f);
    float var = sq * (1.f / 512.f) - mean * mean;
    float rr = rsqrtf(var + 1e-5f);
    #pragma unroll
    for (int cc = 0; cc < 8; ++cc) {
      unsigned u[4];
      #pragma unroll
      for (int q = 0; q < 4; ++q) {
        int c0 = cb + cc * 8 + 2 * q;
        float y0 = elu((h[cc * 8 + 2 * q]     - mean) * rr * g1s[c0]     + be1s[c0]);
        float y1 = elu((h[cc * 8 + 2 * q + 1] - mean) * rr * g1s[c0 + 1] + be1s[c0 + 1]);
        u[q] = pack2bf(y0, y1);
      }
      *(uint4v*)&H[row * 520 + cb + cc * 8] = *(uint4v*)u;
    }
  }
  __syncthreads();
  // ---- phase 2: wave owns n-quarter (64 cols), both m-tiles. B read once per block. ----
  int quad = lane >> 4, l16 = lane & 15;
  int cb2 = wave * 64;
  f32x4 acc2[2][4] = {};
  #pragma unroll 4
  for (int ks = 0; ks < 16; ++ks) {
    bf16x8 bvv[4];
    #pragma unroll
    for (int ni = 0; ni < 4; ++ni)
      bvv[ni] = *(const bf16x8*)(B2p + ((size_t)(ks * 16 + wave * 4 + ni) * 64 + lane) * 8);
    bf16x8 a0 = __builtin_bit_cast(bf16x8, *(const uint4v*)&H[(l16) * 520 + ks * 32 + quad * 8]);
    bf16x8 a1 = __builtin_bit_cast(bf16x8, *(const uint4v*)&H[(16 + l16) * 520 + ks * 32 + quad * 8]);
    #pragma unroll
    for (int ni = 0; ni < 4; ++ni) {
      acc2[0][ni] = __builtin_amdgcn_mfma_f32_16x16x32_bf16(a0, bvv[ni], acc2[0][ni], 0, 0, 0);
      acc2[1][ni] = __builtin_amdgcn_mfma_f32_16x16x32_bf16(a1, bvv[ni], acc2[1][ni], 0, 0, 0);
    }
  }
  float b2v[4], g2v[4], be2v[4];
  #pragma unroll
  for (int ni = 0; ni < 4; ++ni) {
    int col = cb2 + ni * 16 + l16;
    b2v[ni] = bias2[col]; g2v[ni] = g2[col]; be2v[ni] = be2[col];
  }
  #pragma unroll
  for (int mt = 0; mt < 2; ++mt)
    #pragma unroll
    for (int r = 0; r < 4; ++r) {
      int row = mt * 16 + quad * 4 + r;
      float s2 = 0.f, q2 = 0.f;
      #pragma unroll
      for (int ni = 0; ni < 4; ++ni) {
        float val = acc2[mt][ni][r] + b2v[ni];
        acc2[mt][ni][r] = val; s2 += val; q2 += val * val;
      }
      #pragma unroll
      for (int off = 1; off < 16; off <<= 1) { s2 += __shfl_xor(s2, off, 64); q2 += __shfl_xor(q2, off, 64); }
      if (l16 == 0) { lnsum[wave * 32 + row] = s2; lnsq[wave * 32 + row] = q2; }
    }
  __syncthreads();
  #pragma unroll
  for (int mt = 0; mt < 2; ++mt)
    #pragma unroll
    for (int r = 0; r < 4; ++r) {
      int row = mt * 16 + quad * 4 + r;
      float tot = lnsum[row] + lnsum[32 + row] + lnsum[64 + row] + lnsum[96 + row];
      float tsq = lnsq[row] + lnsq[32 + row] + lnsq[64 + row] + lnsq[96 + row];
      float mean = tot * (1.f / 256.f);
      float var = tsq * (1.f / 256.f) - mean * mean;
      float rr = rsqrtf(var + 1e-5f);
      size_t ob = (size_t)(el0 + row) * 256;
      #pragma unroll
      for (int ni = 0; ni < 4; ++ni)
        delta_b[ob + cb2 + ni * 16 + l16] =
            f2bf_fast(elu((acc2[mt][ni][r] - mean) * rr * g2v[ni] + be2v[ni]));
    }
}

// ================= attn fused: LDS t-tile; both phases Mt=2, wave owns n-quarter =================
// smem: As[32][264] @0 (16896) | H[32][520] @16896 (33280) | lnsum @50176 | lnsq @50688 | iS/jS @51200
__global__ __launch_bounds__(256)
void attn_fused(const unsigned short* __restrict__ qkv,
                const unsigned short* __restrict__ delta_b,
                const int* __restrict__ neigh,
                const unsigned short* __restrict__ B1p, const float* __restrict__ bias1,
                const float* __restrict__ g1, const float* __restrict__ be1,
                const unsigned short* __restrict__ B2p, const float* __restrict__ bias2,
                const float* __restrict__ g2, const float* __restrict__ be2,
                unsigned short* __restrict__ alpha_b, int edge_base) {
  __shared__ alignas(16) char smem[51456];
  unsigned short* As = (unsigned short*)smem;                  // [32][264]
  unsigned short* H  = (unsigned short*)(smem + 16896);        // [32][520]
  float* lnsum = (float*)(smem + 50176);                       // [4][32]
  float* lnsq  = (float*)(smem + 50688);                       // [4][32]
  int* iS = (int*)(smem + 51200);
  int* jS = (int*)(smem + 51328);
  int tid = threadIdx.x;
  int wave = tid >> 6, lane = tid & 63;
  int quad = lane >> 4, l16 = lane & 15;
  int el0 = blockIdx.x * 32;
  int eg0 = edge_base + el0;
  if (tid < 32) { iS[tid] = (eg0 + tid) / KNN; jS[tid] = neigh[eg0 + tid]; }
  __syncthreads();
  // ---- build t tile once: row = tid&31, seg = tid>>5 (32 cols each) ----
  {
    int r = tid & 31, seg = tid >> 5;
    int i = iS[r], j = jS[r], e = el0 + r;
    int c0 = seg * 32;
    #pragma unroll
    for (int q4 = 0; q4 < 4; ++q4) {
      int c = c0 + q4 * 8;
      us8 pd = *(const us8*)(qkv + (size_t)i * QS + 256 + c);
      us8 ps = *(const us8*)(qkv + (size_t)j * QS + c);
      us8 pl = *(const us8*)(delta_b + (size_t)e * 256 + c);
      unsigned u[4];
      #pragma unroll
      for (int q = 0; q < 4; ++q)
        u[q] = pack2bf(bf2f(pd[2*q])   - bf2f(ps[2*q])   + bf2f(pl[2*q]),
                       bf2f(pd[2*q+1]) - bf2f(ps[2*q+1]) + bf2f(pl[2*q+1]));
      *(uint4v*)&As[r * 264 + c] = *(uint4v*)u;
    }
  }
  __syncthreads();
  // ---- phase 1: K=256; wave owns n-quarter (128 cols), both m-tiles ----
  int cb1 = wave * 128;
  f32x4 acc1[2][8] = {};
  #pragma unroll 2
  for (int ks = 0; ks < 8; ++ks) {
    bf16x8 bvv[8];
    #pragma unroll
    for (int ni = 0; ni < 8; ++ni)
      bvv[ni] = *(const bf16x8*)(B1p + ((size_t)(ks * 32 + wave * 8 + ni) * 64 + lane) * 8);
    bf16x8 a0 = __builtin_bit_cast(bf16x8, *(const uint4v*)&As[(l16) * 264 + ks * 32 + quad * 8]);
    bf16x8 a1 = __builtin_bit_cast(bf16x8, *(const uint4v*)&As[(16 + l16) * 264 + ks * 32 + quad * 8]);
    #pragma unroll
    for (int ni = 0; ni < 8; ++ni) {
      acc1[0][ni] = __builtin_amdgcn_mfma_f32_16x16x32_bf16(a0, bvv[ni], acc1[0][ni], 0, 0, 0);
      acc1[1][ni] = __builtin_amdgcn_mfma_f32_16x16x32_bf16(a1, bvv[ni], acc1[1][ni], 0, 0, 0);
    }
  }
  // epilogue 1: bias + 4-partial LN stats
  {
    float b1v[8], g1v[8], be1v[8];
    #pragma unroll
    for (int ni = 0; ni < 8; ++ni) {
      int col = cb1 + ni * 16 + l16;
      b1v[ni] = bias1[col]; g1v[ni] = g1[col]; be1v[ni] = be1[col];
    }
    #pragma unroll
    for (int mt = 0; mt < 2; ++mt)
      #pragma unroll
      for (int r = 0; r < 4; ++r) {
        int row = mt * 16 + quad * 4 + r;
        float s = 0.f, sq = 0.f;
        #pragma unroll
        for (int ni = 0; ni < 8; ++ni) {
          float val = acc1[mt][ni][r] + b1v[ni];
          acc1[mt][ni][r] = val; s += val; sq += val * val;
        }
        #pragma unroll
        for (int off = 1; off < 16; off <<= 1) { s += __shfl_xor(s, off, 64); sq += __shfl_xor(sq, off, 64); }
        if (l16 == 0) { lnsum[wave * 32 + row] = s; lnsq[wave * 32 + row] = sq; }
      }
    __syncthreads();
    #pragma unroll
    for (int mt = 0; mt < 2; ++mt)
      #pragma unroll
      for (int r = 0; r < 4; ++r) {
        int row = mt * 16 + quad * 4 + r;
        float tot = lnsum[row] + lnsum[32 + row] + lnsum[64 + row] + lnsum[96 + row];
        float tsq = lnsq[row] + lnsq[32 + row] + lnsq[64 + row] + lnsq[96 + row];
        float mean = tot * (1.f / 512.f);
        float var = tsq * (1.f / 512.f) - mean * mean;
        float rr = rsqrtf(var + 1e-5f);
        #pragma unroll
        for (int ni = 0; ni < 8; ++ni) {
          int col = cb1 + ni * 16 + l16;
          H[row * 520 + col] = f2bf_fast(elu((acc1[mt][ni][r] - mean) * rr * g1v[ni] + be1v[ni]));
        }
      }
  }
  __syncthreads();
  // ---- phase 2: K=512; wave owns n-quarter (64 cols), both m-tiles ----
  int cb2 = wave * 64;
  f32x4 acc2[2][4] = {};
  #pragma unroll 4
  for (int ks = 0; ks < 16; ++ks) {
    bf16x8 bvv[4];
    #pragma unroll
    for (int ni = 0; ni < 4; ++ni)
      bvv[ni] = *(const bf16x8*)(B2p + ((size_t)(ks * 16 + wave * 4 + ni) * 64 + lane) * 8);
    bf16x8 a0 = __builtin_bit_cast(bf16x8, *(const uint4v*)&H[(l16) * 520 + ks * 32 + quad * 8]);
    bf16x8 a1 = __builtin_bit_cast(bf16x8, *(const uint4v*)&H[(16 + l16) * 520 + ks * 32 + quad * 8]);
    #pragma unroll
    for (int ni = 0; ni < 4; ++ni) {
      acc2[0][ni] = __builtin_amdgcn_mfma_f32_16x16x32_bf16(a0, bvv[ni], acc2[0][ni], 0, 0, 0);
      acc2[1][ni] = __builtin_amdgcn_mfma_f32_16x16x32_bf16(a1, bvv[ni], acc2[1][ni], 0, 0, 0);
    }
  }
  float b2v[4], g2v[4], be2v[4];
  #pragma unroll
  for (int ni = 0; ni < 4; ++ni) {
    int col = cb2 + ni * 16 + l16;
    b2v[ni] = bias2[col]; g2v[ni] = g2[col]; be2v[ni] = be2[col];
  }
  #pragma unroll
  for (int mt = 0; mt < 2; ++mt)
    #pragma unroll
    for (int r = 0; r < 4; ++r) {
      int row = mt * 16 + quad * 4 + r;
      float s2 = 0.f, q2 = 0.f;
      #pragma unroll
      for (int ni = 0; ni < 4; ++ni) {
        float val = acc2[mt][ni][r] + b2v[ni];
        acc2[mt][ni][r] = val; s2 += val; q2 += val * val;
      }
      #pragma unroll
      for (int off = 1; off < 16; off <<= 1) { s2 += __shfl_xor(s2, off, 64); q2 += __shfl_xor(q2, off, 64); }
      if (l16 == 0) { lnsum[wave * 32 + row] = s2; lnsq[wave * 32 + row] = q2; }
    }
  __syncthreads();
  #pragma unroll
  for (int mt = 0; mt < 2; ++mt)
    #pragma unroll
    for (int r = 0; r < 4; ++r) {
      int row = mt * 16 + quad * 4 + r;
      float tot = lnsum[row] + lnsum[32 + row] + lnsum[64 + row] + lnsum[96 + row];
      float tsq = lnsq[row] + lnsq[32 + row] + lnsq[64 + row] + lnsq[96 + row];
      float mean = tot * (1.f / 256.f);
      float var = tsq * (1.f / 256.f) - mean * mean;
      float rr = rsqrtf(var + 1e-5f);
      size_t ob = (size_t)(el0 + row) * 256;
      #pragma unroll
      for (int ni = 0; ni < 4; ++ni)
        alpha_b[ob + cb2 + ni * 16 + l16] =
            f2bf_fast(elu((acc2[mt][ni][r] - mean) * rr * g2v[ni] + be2v[ni]));
    }
}

// ---------------- plain bf16 MFMA GEMM ----------------
#define APAD 40
__global__ __launch_bounds__(256)
void gemm_mfma(const unsigned short* __restrict__ A, const unsigned short* __restrict__ Bt,
               const float* __restrict__ bias, float* __restrict__ Cf,
               unsigned short* __restrict__ Cb, int M, int Nn, int Kk) {
  __shared__ alignas(16) unsigned short As[128 * APAD];
  __shared__ alignas(16) unsigned short Bs[128 * APAD];
  int tid = threadIdx.x;
  int wave = tid >> 6, lane = tid & 63;
  int quad = lane >> 4, l16 = lane & 15;
  int wm = (wave >> 1) * 64, wn = (wave & 1) * 64;
  int m0 = blockIdx.y * 128, n0 = blockIdx.x * 128;
  f32x4 acc[4][4] = {};
  int srow = tid >> 2;
  int scol = (tid & 3) * 8;
  for (int k0 = 0; k0 < Kk; k0 += 32) {
    #pragma unroll
    for (int h = 0; h < 2; ++h) {
      int r = srow + h * 64;
      int gm = m0 + r;
      uint4v va = {0, 0, 0, 0};
      if (gm < M) va = *(const uint4v*)(A + (size_t)gm * Kk + k0 + scol);
      *(uint4v*)(&As[r * APAD + scol]) = va;
      int gn = n0 + r;
      uint4v vb = *(const uint4v*)(Bt + (size_t)gn * Kk + k0 + scol);
      *(uint4v*)(&Bs[r * APAD + scol]) = vb;
    }
    __syncthreads();
    bf16x8 af[4], bfr[4];
    #pragma unroll
    for (int mi = 0; mi < 4; ++mi)
      af[mi] = __builtin_bit_cast(bf16x8, *(const uint4v*)(&As[(wm + mi * 16 + l16) * APAD + quad * 8]));
    #pragma unroll
    for (int ni = 0; ni < 4; ++ni)
      bfr[ni] = __builtin_bit_cast(bf16x8, *(const uint4v*)(&Bs[(wn + ni * 16 + l16) * APAD + quad * 8]));
    #pragma unroll
    for (int mi = 0; mi < 4; ++mi)
      #pragma unroll
      for (int ni = 0; ni < 4; ++ni)
        acc[mi][ni] = __builtin_amdgcn_mfma_f32_16x16x32_bf16(af[mi], bfr[ni], acc[mi][ni], 0, 0, 0);
    __syncthreads();
  }
  float bvs[4]; int gns[4];
  #pragma unroll
  for (int ni = 0; ni < 4; ++ni) {
    gns[ni] = n0 + wn + ni * 16 + l16;
    bvs[ni] = bias ? bias[gns[ni]] : 0.f;
  }
  #pragma unroll
  for (int mi = 0; mi < 4; ++mi) {
    #pragma unroll
    for (int r = 0; r < 4; ++r) {
      int gm = m0 + wm + mi * 16 + quad * 4 + r;
      if (gm >= M) continue;
      #pragma unroll
      for (int ni = 0; ni < 4; ++ni) {
        float val = acc[mi][ni][r] + bvs[ni];
        if (Cf) Cf[(size_t)gm * Nn + gns[ni]] = val;
        if (Cb) Cb[(size_t)gm * Nn + gns[ni]] = f2bf_fast(val);
      }
    }
  }
}

// ---------------- fp32 tiled GEMM (head only, M=8) ----------------
#define BM0 64
#define BN0 64
#define BK0 16
__global__ __launch_bounds__(256)
void gemm_bias(const float* __restrict__ A, const float* __restrict__ Bw,
               const float* __restrict__ bias, float* __restrict__ C,
               int M, int Nn, int Kk) {
  __shared__ float Asm[BK0][BM0 + 1];
  __shared__ float Bsm[BK0][BN0 + 1];
  int bm = blockIdx.y * BM0, bn = blockIdx.x * BN0;
  int tid = threadIdx.x;
  int tx = tid & 15, ty = tid >> 4;
  float acc[4][4] = {{0.f}};
  for (int k0 = 0; k0 < Kk; k0 += BK0) {
    #pragma unroll
    for (int ii = 0; ii < 4; ++ii) {
      int e = tid + ii * 256;
      int m = e >> 4, k = e & 15;
      int gm = bm + m, gk = k0 + k;
      Asm[k][m] = (gm < M && gk < Kk) ? A[(size_t)gm * Kk + gk] : 0.f;
    }
    #pragma unroll
    for (int ii = 0; ii < 4; ++ii) {
      int e = tid + ii * 256;
      int k = e >> 6, n = e & 63;
      int gk = k0 + k, gn = bn + n;
      Bsm[k][n] = (gk < Kk && gn < Nn) ? Bw[(size_t)gk * Nn + gn] : 0.f;
    }
    __syncthreads();
    #pragma unroll
    for (int kk = 0; kk < BK0; ++kk) {
      float a[4], b[4];
      #pragma unroll
      for (int ii = 0; ii < 4; ++ii) a[ii] = Asm[kk][ty * 4 + ii];
      #pragma unroll
      for (int jj = 0; jj < 4; ++jj) b[jj] = Bsm[kk][tx * 4 + jj];
      #pragma unroll
      for (int ii = 0; ii < 4; ++ii)
        #pragma unroll
        for (int jj = 0; jj < 4; ++jj)
          acc[ii][jj] += a[ii] * b[jj];
    }
    __syncthreads();
  }
  #pragma unroll
  for (int ii = 0; ii < 4; ++ii) {
    int gm = bm + ty * 4 + ii;
    if (gm >= M) continue;
    #pragma unroll
    for (int jj = 0; jj < 4; ++jj) {
      int gn = bn + tx * 4 + jj;
      if (gn >= Nn) continue;
      float vv = acc[ii][jj];
      if (bias) vv += bias[gn];
      C[(size_t)gm * Nn + gn] = vv;
    }
  }
}

// ---------------- LayerNorm + ELU (tail & head) ----------------
__global__ __launch_bounds__(256)
void ln_elu_kernel(const float* __restrict__ in, float* __restrict__ outf,
                   unsigned short* __restrict__ outb,
                   const float* __restrict__ g, const float* __restrict__ bb,
                   int Cn, int do_elu) {
  __shared__ float sdata[4];
  size_t row = blockIdx.x;
  const float* x = in + row * Cn;
  int tid = threadIdx.x;
  float v0 = x[tid];
  float v1 = (Cn == 512) ? x[tid + 256] : 0.f;
  float s = v0 + v1;
  #pragma unroll
  for (int off = 32; off > 0; off >>= 1) s += __shfl_xor(s, off, 64);
  if ((tid & 63) == 0) sdata[tid >> 6] = s;
  __syncthreads();
  float mean = (sdata[0] + sdata[1] + sdata[2] + sdata[3]) / (float)Cn;
  float d0 = v0 - mean;
  float d1 = (Cn == 512) ? (v1 - mean) : 0.f;
  float sq = d0 * d0 + d1 * d1;
  __syncthreads();
  #pragma unroll
  for (int off = 32; off > 0; off >>= 1) sq += __shfl_xor(sq, off, 64);
  if ((tid & 63) == 0) sdata[tid >> 6] = sq;
  __syncthreads();
  float var = (sdata[0] + sdata[1] + sdata[2] + sdata[3]) / (float)Cn;
  float r = rsqrtf(var + 1e-5f);
  float y0 = d0 * r * g[tid] + bb[tid];
  if (do_elu) y0 = elu(y0);
  if (outf) outf[row * Cn + tid] = y0;
  if (outb) outb[row * Cn + tid] = f2bf_fast(y0);
  if (Cn == 512) {
    float y1 = d1 * r * g[tid + 256] + bb[tid + 256];
    if (do_elu) y1 = elu(y1);
    if (outf) outf[row * Cn + tid + 256] = y1;
    if (outb) outb[row * Cn + tid + 256] = f2bf_fast(y1);
  }
}

// ---------------- per-channel softmax over K + weighted aggregation ----------------
__global__ __launch_bounds__(256)
void softmax_agg(const unsigned short* __restrict__ alpha_b,
                 const unsigned short* __restrict__ delta_b,
                 const unsigned short* __restrict__ qkv,
                 const int* __restrict__ neigh,
                 float* __restrict__ agg, int node0) {
  int nl = blockIdx.x;
  int c = threadIdx.x;
  int i = node0 + nl;
  float av[KNN];
  float mx = -3.4e38f;
  #pragma unroll
  for (int k = 0; k < KNN; ++k) {
    av[k] = bf2f(alpha_b[((size_t)nl * KNN + k) * HDIM + c]);
    mx = fmaxf(mx, av[k]);
  }
  float ssum = 0.f;
  #pragma unroll
  for (int k = 0; k < KNN; ++k) { av[k] = __expf(av[k] - mx); ssum += av[k]; }
  float inv = 1.f / ssum;
  float acc = 0.f;
  #pragma unroll
  for (int k = 0; k < KNN; ++k) {
    int j = neigh[(size_t)i * KNN + k];
    acc += av[k] * inv * (bf2f(qkv[(size_t)j * QS + 512 + c]) +
                          bf2f(delta_b[((size_t)nl * KNN + k) * HDIM + c]));
  }
  agg[(size_t)i * HDIM + c] = acc;
}

// ---------------- x += res_alpha[l] * h ; xb = bf16(x) ----------------
__global__ __launch_bounds__(256)
void axpy_res(float* __restrict__ x, unsigned short* __restrict__ xb,
              const float* __restrict__ h, const float* __restrict__ alpha, int l) {
  size_t idx = (size_t)blockIdx.x * 256 + threadIdx.x;
  float nv = x[idx] + alpha[l] * h[idx];
  x[idx] = nv;
  xb[idx] = f2bf_fast(nv);
}

// ---------------- global max pool, two-stage ----------------
__global__ __launch_bounds__(256)
void seg_max_p(const float* __restrict__ h, float* __restrict__ part) {
  int blk = blockIdx.x;
  int b = blk >> 4, ch = blk & 15;
  int c = threadIdx.x;
  const float* base = h + ((size_t)b * PPC + (size_t)ch * 64) * HDIM;
  float m = -3.4e38f;
  for (int p = 0; p < 64; ++p)
    m = fmaxf(m, base[(size_t)p * HDIM + c]);
  part[(size_t)blk * HDIM + c] = m;
}
__global__ __launch_bounds__(256)
void seg_max_f(const float* __restrict__ part, float* __restrict__ pooled) {
  int b = blockIdx.x;
  int c = threadIdx.x;
  float m = -3.4e38f;
  for (int k = 0; k < 16; ++k)
    m = fmaxf(m, part[(size_t)(b * 16 + k) * HDIM + c]);
  pooled[(size_t)b * HDIM + c] = m;
}

extern "C" void kernel_launch(void* const* d_in, const int* in_sizes, int n_in,
                              void* d_out, int out_size, void* d_ws, size_t ws_size,
                              hipStream_t stream) {
  const float* pos       = (const float*)d_in[0];
  const float* ffm_W     = (const float*)d_in[2];
  const float* ffm_b     = (const float*)d_in[3];
  const float* lin_W     = (const float*)d_in[4];
  const float* src_W     = (const float*)d_in[5];
  const float* dst_W     = (const float*)d_in[6];
  const float* pos1_W    = (const float*)d_in[7];
  const float* pos1_b    = (const float*)d_in[8];
  const float* pos_ln1_g = (const float*)d_in[9];
  const float* pos_ln1_b = (const float*)d_in[10];
  const float* pos2_W    = (const float*)d_in[11];
  const float* pos2_b    = (const float*)d_in[12];
  const float* pos_ln2_g = (const float*)d_in[13];
  const float* pos_ln2_b = (const float*)d_in[14];
  const float* att1_W    = (const float*)d_in[15];
  const float* att1_b    = (const float*)d_in[16];
  const float* att_ln1_g = (const float*)d_in[17];
  const float* att_ln1_b = (const float*)d_in[18];
  const float* att2_W    = (const float*)d_in[19];
  const float* att2_b    = (const float*)d_in[20];
  const float* att_ln2_g = (const float*)d_in[21];
  const float* att_ln2_b = (const float*)d_in[22];
  const float* blk_ln_g  = (const float*)d_in[23];
  const float* blk_ln_b  = (const float*)d_in[24];
  const float* blk_W     = (const float*)d_in[25];
  const float* blk_b     = (const float*)d_in[26];
  const float* res_alpha = (const float*)d_in[27];
  const float* r1_W = (const float*)d_in[28]; const float* r1_b = (const float*)d_in[29];
  const float* r2_W = (const float*)d_in[30]; const float* r2_b = (const float*)d_in[31];
  const float* r2_ln_g = (const float*)d_in[32]; const float* r2_ln_b = (const float*)d_in[33];
  const float* r3_W = (const float*)d_in[34]; const float* r3_b = (const float*)d_in[35];
  const float* r3_ln_g = (const float*)d_in[36]; const float* r3_ln_b = (const float*)d_in[37];
  const float* r4_W = (const float*)d_in[38]; const float* r4_b = (const float*)d_in[39];
  float* out = (float*)d_out;

  // ---- workspace carve-up ----
  char* wsp = (char*)d_ws;
  auto alloc = [&](size_t bytes) -> void* {
    void* p = (void*)wsp;
    wsp += (bytes + 255) & ~(size_t)255;
    return p;
  };
  int*            neigh   = (int*)alloc(EDG * sizeof(int));
  float*          rel_f   = (float*)alloc((size_t)EDG * 3 * 4);
  unsigned short* posb    = (unsigned short*)alloc((size_t)NPTS * 32 * 2);
  float*          x       = (float*)alloc((size_t)NPTS * HDIM * 4);
  unsigned short* xb      = (unsigned short*)alloc((size_t)NPTS * HDIM * 2);
  unsigned short* xln_b   = (unsigned short*)alloc((size_t)NPTS * HDIM * 2);
  unsigned short* qkv     = (unsigned short*)alloc((size_t)NPTS * QS * 2);
  float*          agg     = (float*)alloc((size_t)NPTS * HDIM * 4);
  float*          segp    = (float*)alloc((size_t)128 * HDIM * 4);
  float*          pooled  = (float*)alloc((size_t)BCL * HDIM * 4);
  float*          hh      = (float*)alloc((size_t)BCL * HDIM * 4);
  unsigned short* ffmt = (unsigned short*)alloc((size_t)HDIM * 32 * 2);
  unsigned short* r1t  = (unsigned short*)alloc((size_t)HDIM * HDIM * 2);
  unsigned short *qkvt[NL], *blkt[NL];
  unsigned short *pos2p[NL], *att1p[NL], *att2p[NL];
  for (int l = 0; l < NL; ++l) {
    qkvt[l]  = (unsigned short*)alloc((size_t)QS * HDIM * 2);
    blkt[l]  = (unsigned short*)alloc((size_t)HDIM * HDIM * 2);
    pos2p[l] = (unsigned short*)alloc((size_t)HDIM * HD2 * 2);   // packed
    att1p[l] = (unsigned short*)alloc((size_t)HD2 * HDIM * 2);   // packed
    att2p[l] = (unsigned short*)alloc((size_t)HDIM * HD2 * 2);   // packed
  }
  // chunked edge buffers: delta + alpha (bf16)
  size_t used = (size_t)(wsp - (char*)d_ws);
  size_t avail = (ws_size > used) ? (ws_size - used) : 0;
  size_t per_node = (size_t)KNN * (HDIM * 2 * 2) + 1024;
  int Nc = (int)(avail / per_node);
  if (Nc > NPTS) Nc = NPTS;
  Nc &= ~15;
  if (Nc < 16) Nc = 16;
  unsigned short* delta_b = (unsigned short*)alloc((size_t)Nc * KNN * HDIM * 2);
  unsigned short* alpha_b = (unsigned short*)alloc((size_t)Nc * KNN * HDIM * 2);

  auto mgemm = [&](const unsigned short* A, const unsigned short* Bt, const float* bias,
                   float* Cf, unsigned short* Cb, int M, int Nn, int Kk) {
    dim3 g(Nn / 128, (M + 127) / 128);
    gemm_mfma<<<g, dim3(256), 0, stream>>>(A, Bt, bias, Cf, Cb, M, Nn, Kk);
  };
  auto fgemm = [&](const float* A, const float* Bw, const float* bias, float* Cp,
                   int M, int Nn, int Kk) {
    dim3 g((Nn + BN0 - 1) / BN0, (M + BM0 - 1) / BM0);
    gemm_bias<<<g, dim3(256), 0, stream>>>(A, Bw, bias, Cp, M, Nn, Kk);
  };

  // ---- weight prep ----
  transpose_w<<<HDIM, 256, 0, stream>>>(ffm_W, ffmt, 3, HDIM, 32);
  transpose_w<<<HDIM, 256, 0, stream>>>(r1_W, r1t, HDIM, HDIM, HDIM);
  for (int l = 0; l < NL; ++l) {
    transpose_w<<<HDIM, 256, 0, stream>>>(src_W + (size_t)l * HDIM * HDIM, qkvt[l], HDIM, HDIM, HDIM);
    transpose_w<<<HDIM, 256, 0, stream>>>(dst_W + (size_t)l * HDIM * HDIM, qkvt[l] + 256 * 256, HDIM, HDIM, HDIM);
    transpose_w<<<HDIM, 256, 0, stream>>>(lin_W + (size_t)l * HDIM * HDIM, qkvt[l] + 512 * 256, HDIM, HDIM, HDIM);
    transpose_w<<<HDIM, 256, 0, stream>>>(blk_W + (size_t)l * HDIM * HDIM, blkt[l], HDIM, HDIM, HDIM);
    pack_w<<<(HD2 / 32) * (HDIM / 16), 64, 0, stream>>>(pos2_W + (size_t)l * HD2 * HDIM, pos2p[l], HDIM);
    pack_w<<<(HDIM / 32) * (HD2 / 16), 64, 0, stream>>>(att1_W + (size_t)l * HDIM * HD2, att1p[l], HD2);
    pack_w<<<(HD2 / 32) * (HDIM / 16), 64, 0, stream>>>(att2_W + (size_t)l * HD2 * HDIM, att2p[l], HDIM);
  }

  // ---- graph + stem ----
  knn_wave<<<NPTS / 4, 256, 0, stream>>>(pos, neigh, rel_f);
  prep_pos<<<NPTS * 32 / 256, 256, 0, stream>>>(pos, posb);
  mgemm(posb, ffmt, ffm_b, x, xb, NPTS, HDIM, 32);

  // ---- transformer layers ----
  for (int l = 0; l < NL; ++l) {
    mgemm(xb, qkvt[l], nullptr, nullptr, qkv, NPTS, QS, HDIM);   // [a_src|a_dst|v]

    for (int n0 = 0; n0 < NPTS; n0 += Nc) {
      int nc = (Nc < NPTS - n0) ? Nc : (NPTS - n0);
      int ec = nc * KNN;
      pos_fused<<<ec / 32, 256, 0, stream>>>(
          rel_f, pos1_W + (size_t)l * 3 * HD2, pos1_b + (size_t)l * HD2,
          pos_ln1_g + (size_t)l * HD2, pos_ln1_b + (size_t)l * HD2,
          pos2p[l], pos2_b + (size_t)l * HDIM,
          pos_ln2_g + (size_t)l * HDIM, pos_ln2_b + (size_t)l * HDIM,
          delta_b, n0 * KNN);
      attn_fused<<<ec / 32, 256, 0, stream>>>(
          qkv, delta_b, neigh,
          att1p[l], att1_b + (size_t)l * HD2,
          att_ln1_g + (size_t)l * HD2, att_ln1_b + (size_t)l * HD2,
          att2p[l], att2_b + (size_t)l * HDIM,
          att_ln2_g + (size_t)l * HDIM, att_ln2_b + (size_t)l * HDIM,
          alpha_b, n0 * KNN);
      softmax_agg<<<nc, 256, 0, stream>>>(alpha_b, delta_b, qkv, neigh, agg, n0);
    }
    ln_elu_kernel<<<NPTS, 256, 0, stream>>>(agg, nullptr, xln_b,
                                            blk_ln_g + (size_t)l * HDIM, blk_ln_b + (size_t)l * HDIM, HDIM, 1);
    mgemm(xln_b, blkt[l], blk_b + (size_t)l * HDIM, agg, nullptr, NPTS, HDIM, HDIM);
    axpy_res<<<(NPTS * HDIM) / 256, 256, 0, stream>>>(x, xb, agg, res_alpha, l);
  }

  // ---- regression head ----
  mgemm(xb, r1t, r1_b, agg, nullptr, NPTS, HDIM, HDIM);
  seg_max_p<<<128, 256, 0, stream>>>(agg, segp);
  seg_max_f<<<BCL, 256, 0, stream>>>(segp, pooled);
  fgemm(pooled, r2_W, r2_b, hh, BCL, HDIM, HDIM);
  ln_elu_kernel<<<BCL, 256, 0, stream>>>(hh, hh, nullptr, r2_ln_g, r2_ln_b, HDIM, 1);
  fgemm(hh, r3_W, r3_b, pooled, BCL, HDIM, HDIM);
  ln_elu_kernel<<<BCL, 256, 0, stream>>>(pooled, pooled, nullptr, r3_ln_g, r3_ln_b, HDIM, 1);
  fgemm(pooled, r4_W, r4_b, out, BCL, NCOMP, HDIM);
}

// Round 10
// 1873.670 us; speedup vs baseline: 1.0953x; 1.0019x over previous
//
#include <hip/hip_runtime.h>
#include <math.h>

#define NPTS 8192
#define PPC  1024
#define BCL  8
#define KNN  20
#define HDIM 256
#define HD2  512
#define NL   3
#define NCOMP 512
#define EDG  (NPTS*KNN)
#define QS   768   // fused qkv row stride: [a_src | a_dst | v]

typedef __bf16 bf16x8 __attribute__((ext_vector_type(8)));
typedef float f32x4 __attribute__((ext_vector_type(4)));
typedef unsigned int uint4v __attribute__((ext_vector_type(4)));
typedef unsigned short us8 __attribute__((ext_vector_type(8)));

__device__ inline unsigned short f2bf(float f) {        // RNE (weight prep)
  unsigned u = __float_as_uint(f);
  u += 0x7FFF + ((u >> 16) & 1);
  return (unsigned short)(u >> 16);
}
__device__ inline unsigned short f2bf_fast(float f) {   // round-half-up, 2 ops
  return (unsigned short)((__float_as_uint(f) + 0x8000u) >> 16);
}
__device__ inline unsigned pack2bf(float a, float b) {  // 2 floats -> packed bf16x2
  return ((__float_as_uint(a) + 0x8000u) >> 16) |
         ((__float_as_uint(b) + 0x8000u) & 0xFFFF0000u);
}
__device__ inline float bf2f(unsigned short u) {
  return __uint_as_float((unsigned)u << 16);
}
__device__ inline float elu(float y) { return (y > 0.f) ? y : (__expf(y) - 1.f); }

// ---------------- KNN: one WAVE per point ----------------
__global__ __launch_bounds__(256)
void knn_wave(const float* __restrict__ pos, int* __restrict__ neigh,
              float* __restrict__ rel_f) {
  __shared__ float px[PPC], py[PPC], pz[PPC];
  int tid = threadIdx.x;
  int i0 = blockIdx.x * 4;
  int base = i0 & ~(PPC - 1);
  for (int t = tid; t < PPC; t += 256) {
    px[t] = pos[(size_t)(base + t) * 3 + 0];
    py[t] = pos[(size_t)(base + t) * 3 + 1];
    pz[t] = pos[(size_t)(base + t) * 3 + 2];
  }
  __syncthreads();
  int wave = tid >> 6, lane = tid & 63;
  int i = i0 + wave;
  int il = i - base;
  float xi = px[il], yi = py[il], zi = pz[il];
  float d[16];
  #pragma unroll
  for (int q = 0; q < 16; ++q) {
    int t = lane + 64 * q;
    float dx = xi - px[t], dy = yi - py[t], dz = zi - pz[t];
    float dd = dx * dx + dy * dy + dz * dz;
    d[q] = (t == il) ? 3.4e38f : dd;
  }
  int mywin = 0;
  for (int k = 0; k < KNN; ++k) {
    float v = d[0]; int idx = lane;
    #pragma unroll
    for (int q = 1; q < 16; ++q)
      if (d[q] < v) { v = d[q]; idx = q * 64 + lane; }
    #pragma unroll
    for (int off = 1; off < 64; off <<= 1) {
      float ov = __shfl_xor(v, off, 64);
      int oi = __shfl_xor(idx, off, 64);
      if (ov < v || (ov == v && oi < idx)) { v = ov; idx = oi; }
    }
    if (lane == k) mywin = idx;
    int qwin = idx >> 6;
    bool own = (idx & 63) == lane;
    #pragma unroll
    for (int q = 0; q < 16; ++q)
      if (own && q == qwin) d[q] = 3.4e38f;
  }
  if (lane < KNN) {
    neigh[(size_t)i * KNN + lane] = base + mywin;
    size_t rb = ((size_t)i * KNN + lane) * 3;
    rel_f[rb + 0] = xi - px[mywin];
    rel_f[rb + 1] = yi - py[mywin];
    rel_f[rb + 2] = zi - pz[mywin];
  }
}

// ---------------- weight prep: fp32 [K][N] -> bf16 [N][Kpad] ----------------
__global__ __launch_bounds__(256)
void transpose_w(const float* __restrict__ W, unsigned short* __restrict__ out,
                 int K, int N, int Kpad) {
  int n = blockIdx.x;
  for (int k = threadIdx.x; k < Kpad; k += 256)
    out[(size_t)n * Kpad + k] = (k < K) ? f2bf(W[(size_t)k * N + n]) : (unsigned short)0;
}

// ---------------- weight prep: fp32 [K][N] -> packed MFMA-fragment order ----------------
// chunk c = ks*(N/16) + nt : 64 lanes x 8 ushorts; lane(l16,quad), j ->
//   B[n = nt*16 + l16][k = ks*32 + quad*8 + j]
__global__ __launch_bounds__(64)
void pack_w(const float* __restrict__ W, unsigned short* __restrict__ out, int N) {
  int blk = blockIdx.x;
  int NT = N / 16;
  int ks = blk / NT, nt = blk % NT;
  int lane = threadIdx.x;
  int l16 = lane & 15, quad = lane >> 4;
  int col = nt * 16 + l16;
  int krow = ks * 32 + quad * 8;
  unsigned short o[8];
  #pragma unroll
  for (int j = 0; j < 8; ++j)
    o[j] = f2bf(W[(size_t)(krow + j) * N + col]);
  *(uint4v*)&out[((size_t)blk * 64 + lane) * 8] = *(uint4v*)o;
}

__global__ __launch_bounds__(256)
void prep_pos(const float* __restrict__ pos, unsigned short* __restrict__ posb) {
  int idx = blockIdx.x * 256 + threadIdx.x;
  int m = idx >> 5, c = idx & 31;
  posb[idx] = (c < 3) ? f2bf(pos[(size_t)m * 3 + c]) : (unsigned short)0;
}

// ================= pos_nn fused: phase2 = Mt=2 x Nt=4 (wave owns n-quarter) =================
__global__ __launch_bounds__(256)
void pos_fused(const float* __restrict__ rel_f, const float* __restrict__ W1,
               const float* __restrict__ b1, const float* __restrict__ g1,
               const float* __restrict__ be1,
               const unsigned short* __restrict__ B2p, const float* __restrict__ bias2,
               const float* __restrict__ g2, const float* __restrict__ be2,
               unsigned short* __restrict__ delta_b, int edge_base) {
  __shared__ alignas(16) char smem[46976];
  unsigned short* H = (unsigned short*)smem;                  // [32][520]
  float* w1s = (float*)(smem + 33280);                        // [3][512]
  float* b1s = w1s + 1536;
  float* g1s = b1s + 512;
  float* be1s = g1s + 512;
  float* lnsum = (float*)(smem + 45568);                      // [4][32]
  float* lnsq  = (float*)(smem + 46080);                      // [4][32]
  float* relS  = (float*)(smem + 46592);                      // [32][3]
  int tid = threadIdx.x;
  int wave = tid >> 6, lane = tid & 63;
  int el0 = blockIdx.x * 32;
  int eg0 = edge_base + el0;
  for (int t = tid; t < 1536; t += 256) w1s[t] = W1[t];
  for (int t = tid; t < 512; t += 256) { b1s[t] = b1[t]; g1s[t] = g1[t]; be1s[t] = be1[t]; }
  if (tid < 96) relS[tid] = rel_f[(size_t)eg0 * 3 + tid];
  __syncthreads();
  // ---- phase 1: rank-3 VALU fp32; row = 8 consecutive lanes ----
  {
    int rIW = lane >> 3, sub = lane & 7;
    int row = wave * 8 + rIW;
    float r0 = relS[row * 3 + 0], r1v = relS[row * 3 + 1], r2v = relS[row * 3 + 2];
    int cb = sub * 64;
    float h[64]; float s = 0.f, sq = 0.f;
    #pragma unroll
    for (int cc = 0; cc < 16; ++cc) {
      f32x4 w0 = *(const f32x4*)&w1s[cb + cc * 4];
      f32x4 wa = *(const f32x4*)&w1s[512 + cb + cc * 4];
      f32x4 wb = *(const f32x4*)&w1s[1024 + cb + cc * 4];
      f32x4 bb = *(const f32x4*)&b1s[cb + cc * 4];
      #pragma unroll
      for (int q = 0; q < 4; ++q) {
        float hv = fmaf(r0, w0[q], fmaf(r1v, wa[q], fmaf(r2v, wb[q], bb[q])));
        h[cc * 4 + q] = hv; s += hv; sq += hv * hv;
      }
    }
    #pragma unroll
    for (int off = 1; off < 8; off <<= 1) { s += __shfl_xor(s, off, 64); sq += __shfl_xor(sq, off, 64); }
    float mean = s * (1.f / 512.f);
    float var = sq * (1.f / 512.f) - mean * mean;
    float rr = rsqrtf(var + 1e-5f);
    #pragma unroll
    for (int cc = 0; cc < 8; ++cc) {
      unsigned u[4];
      #pragma unroll
      for (int q = 0; q < 4; ++q) {
        int c0 = cb + cc * 8 + 2 * q;
        float y0 = elu((h[cc * 8 + 2 * q]     - mean) * rr * g1s[c0]     + be1s[c0]);
        float y1 = elu((h[cc * 8 + 2 * q + 1] - mean) * rr * g1s[c0 + 1] + be1s[c0 + 1]);
        u[q] = pack2bf(y0, y1);
      }
      *(uint4v*)&H[row * 520 + cb + cc * 8] = *(uint4v*)u;
    }
  }
  __syncthreads();
  // ---- phase 2: wave owns n-quarter (64 cols), both m-tiles. B read once per block. ----
  int quad = lane >> 4, l16 = lane & 15;
  int cb2 = wave * 64;
  f32x4 acc2[2][4] = {};
  #pragma unroll 4
  for (int ks = 0; ks < 16; ++ks) {
    bf16x8 bvv[4];
    #pragma unroll
    for (int ni = 0; ni < 4; ++ni)
      bvv[ni] = *(const bf16x8*)(B2p + ((size_t)(ks * 16 + wave * 4 + ni) * 64 + lane) * 8);
    bf16x8 a0 = __builtin_bit_cast(bf16x8, *(const uint4v*)&H[(l16) * 520 + ks * 32 + quad * 8]);
    bf16x8 a1 = __builtin_bit_cast(bf16x8, *(const uint4v*)&H[(16 + l16) * 520 + ks * 32 + quad * 8]);
    #pragma unroll
    for (int ni = 0; ni < 4; ++ni) {
      acc2[0][ni] = __builtin_amdgcn_mfma_f32_16x16x32_bf16(a0, bvv[ni], acc2[0][ni], 0, 0, 0);
      acc2[1][ni] = __builtin_amdgcn_mfma_f32_16x16x32_bf16(a1, bvv[ni], acc2[1][ni], 0, 0, 0);
    }
  }
  float b2v[4], g2v[4], be2v[4];
  #pragma unroll
  for (int ni = 0; ni < 4; ++ni) {
    int col = cb2 + ni * 16 + l16;
    b2v[ni] = bias2[col]; g2v[ni] = g2[col]; be2v[ni] = be2[col];
  }
  #pragma unroll
  for (int mt = 0; mt < 2; ++mt)
    #pragma unroll
    for (int r = 0; r < 4; ++r) {
      int row = mt * 16 + quad * 4 + r;
      float s2 = 0.f, q2 = 0.f;
      #pragma unroll
      for (int ni = 0; ni < 4; ++ni) {
        float val = acc2[mt][ni][r] + b2v[ni];
        acc2[mt][ni][r] = val; s2 += val; q2 += val * val;
      }
      #pragma unroll
      for (int off = 1; off < 16; off <<= 1) { s2 += __shfl_xor(s2, off, 64); q2 += __shfl_xor(q2, off, 64); }
      if (l16 == 0) { lnsum[wave * 32 + row] = s2; lnsq[wave * 32 + row] = q2; }
    }
  __syncthreads();
  #pragma unroll
  for (int mt = 0; mt < 2; ++mt)
    #pragma unroll
    for (int r = 0; r < 4; ++r) {
      int row = mt * 16 + quad * 4 + r;
      float tot = lnsum[row] + lnsum[32 + row] + lnsum[64 + row] + lnsum[96 + row];
      float tsq = lnsq[row] + lnsq[32 + row] + lnsq[64 + row] + lnsq[96 + row];
      float mean = tot * (1.f / 256.f);
      float var = tsq * (1.f / 256.f) - mean * mean;
      float rr = rsqrtf(var + 1e-5f);
      size_t ob = (size_t)(el0 + row) * 256;
      #pragma unroll
      for (int ni = 0; ni < 4; ++ni)
        delta_b[ob + cb2 + ni * 16 + l16] =
            f2bf_fast(elu((acc2[mt][ni][r] - mean) * rr * g2v[ni] + be2v[ni]));
    }
}

// ================= attn fused: As/H ALIASED in LDS; both phases Mt=2, wave owns n-quarter =================
// smem union @0: As[32][264] (16896 B, phase-1 only) / H[32][520] (33280 B, written after
// the post-k-loop barrier — every wave is done reading As by then). Then lnsum/lnsq/iS/jS.
__global__ __launch_bounds__(256)
void attn_fused(const unsigned short* __restrict__ qkv,
                const unsigned short* __restrict__ delta_b,
                const int* __restrict__ neigh,
                const unsigned short* __restrict__ B1p, const float* __restrict__ bias1,
                const float* __restrict__ g1, const float* __restrict__ be1,
                const unsigned short* __restrict__ B2p, const float* __restrict__ bias2,
                const float* __restrict__ g2, const float* __restrict__ be2,
                unsigned short* __restrict__ alpha_b, int edge_base) {
  __shared__ alignas(16) char smem[34560];
  unsigned short* As = (unsigned short*)smem;                  // [32][264] (phase 1)
  unsigned short* H  = (unsigned short*)smem;                  // [32][520] (aliases As)
  float* lnsum = (float*)(smem + 33280);                       // [4][32]
  float* lnsq  = (float*)(smem + 33792);                       // [4][32]
  int* iS = (int*)(smem + 34304);
  int* jS = (int*)(smem + 34432);
  int tid = threadIdx.x;
  int wave = tid >> 6, lane = tid & 63;
  int quad = lane >> 4, l16 = lane & 15;
  int el0 = blockIdx.x * 32;
  int eg0 = edge_base + el0;
  if (tid < 32) { iS[tid] = (eg0 + tid) / KNN; jS[tid] = neigh[eg0 + tid]; }
  __syncthreads();
  // ---- build t tile once: row = tid&31, seg = tid>>5 (32 cols each) ----
  {
    int r = tid & 31, seg = tid >> 5;
    int i = iS[r], j = jS[r], e = el0 + r;
    int c0 = seg * 32;
    #pragma unroll
    for (int q4 = 0; q4 < 4; ++q4) {
      int c = c0 + q4 * 8;
      us8 pd = *(const us8*)(qkv + (size_t)i * QS + 256 + c);
      us8 ps = *(const us8*)(qkv + (size_t)j * QS + c);
      us8 pl = *(const us8*)(delta_b + (size_t)e * 256 + c);
      unsigned u[4];
      #pragma unroll
      for (int q = 0; q < 4; ++q)
        u[q] = pack2bf(bf2f(pd[2*q])   - bf2f(ps[2*q])   + bf2f(pl[2*q]),
                       bf2f(pd[2*q+1]) - bf2f(ps[2*q+1]) + bf2f(pl[2*q+1]));
      *(uint4v*)&As[r * 264 + c] = *(uint4v*)u;
    }
  }
  __syncthreads();
  // ---- phase 1: K=256; wave owns n-quarter (128 cols), both m-tiles ----
  int cb1 = wave * 128;
  f32x4 acc1[2][8] = {};
  #pragma unroll 2
  for (int ks = 0; ks < 8; ++ks) {
    bf16x8 bvv[8];
    #pragma unroll
    for (int ni = 0; ni < 8; ++ni)
      bvv[ni] = *(const bf16x8*)(B1p + ((size_t)(ks * 32 + wave * 8 + ni) * 64 + lane) * 8);
    bf16x8 a0 = __builtin_bit_cast(bf16x8, *(const uint4v*)&As[(l16) * 264 + ks * 32 + quad * 8]);
    bf16x8 a1 = __builtin_bit_cast(bf16x8, *(const uint4v*)&As[(16 + l16) * 264 + ks * 32 + quad * 8]);
    #pragma unroll
    for (int ni = 0; ni < 8; ++ni) {
      acc1[0][ni] = __builtin_amdgcn_mfma_f32_16x16x32_bf16(a0, bvv[ni], acc1[0][ni], 0, 0, 0);
      acc1[1][ni] = __builtin_amdgcn_mfma_f32_16x16x32_bf16(a1, bvv[ni], acc1[1][ni], 0, 0, 0);
    }
  }
  // epilogue 1: bias + 4-partial LN stats; barrier; THEN write H (safe: As dead everywhere)
  {
    float b1v[8], g1v[8], be1v[8];
    #pragma unroll
    for (int ni = 0; ni < 8; ++ni) {
      int col = cb1 + ni * 16 + l16;
      b1v[ni] = bias1[col]; g1v[ni] = g1[col]; be1v[ni] = be1[col];
    }
    #pragma unroll
    for (int mt = 0; mt < 2; ++mt)
      #pragma unroll
      for (int r = 0; r < 4; ++r) {
        int row = mt * 16 + quad * 4 + r;
        float s = 0.f, sq = 0.f;
        #pragma unroll
        for (int ni = 0; ni < 8; ++ni) {
          float val = acc1[mt][ni][r] + b1v[ni];
          acc1[mt][ni][r] = val; s += val; sq += val * val;
        }
        #pragma unroll
        for (int off = 1; off < 16; off <<= 1) { s += __shfl_xor(s, off, 64); sq += __shfl_xor(sq, off, 64); }
        if (l16 == 0) { lnsum[wave * 32 + row] = s; lnsq[wave * 32 + row] = sq; }
      }
    __syncthreads();   // all waves past k-loop: As region now reusable as H
    #pragma unroll
    for (int mt = 0; mt < 2; ++mt)
      #pragma unroll
      for (int r = 0; r < 4; ++r) {
        int row = mt * 16 + quad * 4 + r;
        float tot = lnsum[row] + lnsum[32 + row] + lnsum[64 + row] + lnsum[96 + row];
        float tsq = lnsq[row] + lnsq[32 + row] + lnsq[64 + row] + lnsq[96 + row];
        float mean = tot * (1.f / 512.f);
        float var = tsq * (1.f / 512.f) - mean * mean;
        float rr = rsqrtf(var + 1e-5f);
        #pragma unroll
        for (int ni = 0; ni < 8; ++ni) {
          int col = cb1 + ni * 16 + l16;
          H[row * 520 + col] = f2bf_fast(elu((acc1[mt][ni][r] - mean) * rr * g1v[ni] + be1v[ni]));
        }
      }
  }
  __syncthreads();
  // ---- phase 2: K=512; wave owns n-quarter (64 cols), both m-tiles ----
  int cb2 = wave * 64;
  f32x4 acc2[2][4] = {};
  #pragma unroll 4
  for (int ks = 0; ks < 16; ++ks) {
    bf16x8 bvv[4];
    #pragma unroll
    for (int ni = 0; ni < 4; ++ni)
      bvv[ni] = *(const bf16x8*)(B2p + ((size_t)(ks * 16 + wave * 4 + ni) * 64 + lane) * 8);
    bf16x8 a0 = __builtin_bit_cast(bf16x8, *(const uint4v*)&H[(l16) * 520 + ks * 32 + quad * 8]);
    bf16x8 a1 = __builtin_bit_cast(bf16x8, *(const uint4v*)&H[(16 + l16) * 520 + ks * 32 + quad * 8]);
    #pragma unroll
    for (int ni = 0; ni < 4; ++ni) {
      acc2[0][ni] = __builtin_amdgcn_mfma_f32_16x16x32_bf16(a0, bvv[ni], acc2[0][ni], 0, 0, 0);
      acc2[1][ni] = __builtin_amdgcn_mfma_f32_16x16x32_bf16(a1, bvv[ni], acc2[1][ni], 0, 0, 0);
    }
  }
  float b2v[4], g2v[4], be2v[4];
  #pragma unroll
  for (int ni = 0; ni < 4; ++ni) {
    int col = cb2 + ni * 16 + l16;
    b2v[ni] = bias2[col]; g2v[ni] = g2[col]; be2v[ni] = be2[col];
  }
  #pragma unroll
  for (int mt = 0; mt < 2; ++mt)
    #pragma unroll
    for (int r = 0; r < 4; ++r) {
      int row = mt * 16 + quad * 4 + r;
      float s2 = 0.f, q2 = 0.f;
      #pragma unroll
      for (int ni = 0; ni < 4; ++ni) {
        float val = acc2[mt][ni][r] + b2v[ni];
        acc2[mt][ni][r] = val; s2 += val; q2 += val * val;
      }
      #pragma unroll
      for (int off = 1; off < 16; off <<= 1) { s2 += __shfl_xor(s2, off, 64); q2 += __shfl_xor(q2, off, 64); }
      if (l16 == 0) { lnsum[wave * 32 + row] = s2; lnsq[wave * 32 + row] = q2; }
    }
  __syncthreads();
  #pragma unroll
  for (int mt = 0; mt < 2; ++mt)
    #pragma unroll
    for (int r = 0; r < 4; ++r) {
      int row = mt * 16 + quad * 4 + r;
      float tot = lnsum[row] + lnsum[32 + row] + lnsum[64 + row] + lnsum[96 + row];
      float tsq = lnsq[row] + lnsq[32 + row] + lnsq[64 + row] + lnsq[96 + row];
      float mean = tot * (1.f / 256.f);
      float var = tsq * (1.f / 256.f) - mean * mean;
      float rr = rsqrtf(var + 1e-5f);
      size_t ob = (size_t)(el0 + row) * 256;
      #pragma unroll
      for (int ni = 0; ni < 4; ++ni)
        alpha_b[ob + cb2 + ni * 16 + l16] =
            f2bf_fast(elu((acc2[mt][ni][r] - mean) * rr * g2v[ni] + be2v[ni]));
    }
}

// ---------------- plain bf16 MFMA GEMM ----------------
#define APAD 40
__global__ __launch_bounds__(256)
void gemm_mfma(const unsigned short* __restrict__ A, const unsigned short* __restrict__ Bt,
               const float* __restrict__ bias, float* __restrict__ Cf,
               unsigned short* __restrict__ Cb, int M, int Nn, int Kk) {
  __shared__ alignas(16) unsigned short As[128 * APAD];
  __shared__ alignas(16) unsigned short Bs[128 * APAD];
  int tid = threadIdx.x;
  int wave = tid >> 6, lane = tid & 63;
  int quad = lane >> 4, l16 = lane & 15;
  int wm = (wave >> 1) * 64, wn = (wave & 1) * 64;
  int m0 = blockIdx.y * 128, n0 = blockIdx.x * 128;
  f32x4 acc[4][4] = {};
  int srow = tid >> 2;
  int scol = (tid & 3) * 8;
  for (int k0 = 0; k0 < Kk; k0 += 32) {
    #pragma unroll
    for (int h = 0; h < 2; ++h) {
      int r = srow + h * 64;
      int gm = m0 + r;
      uint4v va = {0, 0, 0, 0};
      if (gm < M) va = *(const uint4v*)(A + (size_t)gm * Kk + k0 + scol);
      *(uint4v*)(&As[r * APAD + scol]) = va;
      int gn = n0 + r;
      uint4v vb = *(const uint4v*)(Bt + (size_t)gn * Kk + k0 + scol);
      *(uint4v*)(&Bs[r * APAD + scol]) = vb;
    }
    __syncthreads();
    bf16x8 af[4], bfr[4];
    #pragma unroll
    for (int mi = 0; mi < 4; ++mi)
      af[mi] = __builtin_bit_cast(bf16x8, *(const uint4v*)(&As[(wm + mi * 16 + l16) * APAD + quad * 8]));
    #pragma unroll
    for (int ni = 0; ni < 4; ++ni)
      bfr[ni] = __builtin_bit_cast(bf16x8, *(const uint4v*)(&Bs[(wn + ni * 16 + l16) * APAD + quad * 8]));
    #pragma unroll
    for (int mi = 0; mi < 4; ++mi)
      #pragma unroll
      for (int ni = 0; ni < 4; ++ni)
        acc[mi][ni] = __builtin_amdgcn_mfma_f32_16x16x32_bf16(af[mi], bfr[ni], acc[mi][ni], 0, 0, 0);
    __syncthreads();
  }
  float bvs[4]; int gns[4];
  #pragma unroll
  for (int ni = 0; ni < 4; ++ni) {
    gns[ni] = n0 + wn + ni * 16 + l16;
    bvs[ni] = bias ? bias[gns[ni]] : 0.f;
  }
  #pragma unroll
  for (int mi = 0; mi < 4; ++mi) {
    #pragma unroll
    for (int r = 0; r < 4; ++r) {
      int gm = m0 + wm + mi * 16 + quad * 4 + r;
      if (gm >= M) continue;
      #pragma unroll
      for (int ni = 0; ni < 4; ++ni) {
        float val = acc[mi][ni][r] + bvs[ni];
        if (Cf) Cf[(size_t)gm * Nn + gns[ni]] = val;
        if (Cb) Cb[(size_t)gm * Nn + gns[ni]] = f2bf_fast(val);
      }
    }
  }
}

// ---------------- fp32 tiled GEMM (head only, M=8) ----------------
#define BM0 64
#define BN0 64
#define BK0 16
__global__ __launch_bounds__(256)
void gemm_bias(const float* __restrict__ A, const float* __restrict__ Bw,
               const float* __restrict__ bias, float* __restrict__ C,
               int M, int Nn, int Kk) {
  __shared__ float Asm[BK0][BM0 + 1];
  __shared__ float Bsm[BK0][BN0 + 1];
  int bm = blockIdx.y * BM0, bn = blockIdx.x * BN0;
  int tid = threadIdx.x;
  int tx = tid & 15, ty = tid >> 4;
  float acc[4][4] = {{0.f}};
  for (int k0 = 0; k0 < Kk; k0 += BK0) {
    #pragma unroll
    for (int ii = 0; ii < 4; ++ii) {
      int e = tid + ii * 256;
      int m = e >> 4, k = e & 15;
      int gm = bm + m, gk = k0 + k;
      Asm[k][m] = (gm < M && gk < Kk) ? A[(size_t)gm * Kk + gk] : 0.f;
    }
    #pragma unroll
    for (int ii = 0; ii < 4; ++ii) {
      int e = tid + ii * 256;
      int k = e >> 6, n = e & 63;
      int gk = k0 + k, gn = bn + n;
      Bsm[k][n] = (gk < Kk && gn < Nn) ? Bw[(size_t)gk * Nn + gn] : 0.f;
    }
    __syncthreads();
    #pragma unroll
    for (int kk = 0; kk < BK0; ++kk) {
      float a[4], b[4];
      #pragma unroll
      for (int ii = 0; ii < 4; ++ii) a[ii] = Asm[kk][ty * 4 + ii];
      #pragma unroll
      for (int jj = 0; jj < 4; ++jj) b[jj] = Bsm[kk][tx * 4 + jj];
      #pragma unroll
      for (int ii = 0; ii < 4; ++ii)
        #pragma unroll
        for (int jj = 0; jj < 4; ++jj)
          acc[ii][jj] += a[ii] * b[jj];
    }
    __syncthreads();
  }
  #pragma unroll
  for (int ii = 0; ii < 4; ++ii) {
    int gm = bm + ty * 4 + ii;
    if (gm >= M) continue;
    #pragma unroll
    for (int jj = 0; jj < 4; ++jj) {
      int gn = bn + tx * 4 + jj;
      if (gn >= Nn) continue;
      float vv = acc[ii][jj];
      if (bias) vv += bias[gn];
      C[(size_t)gm * Nn + gn] = vv;
    }
  }
}

// ---------------- LayerNorm + ELU (tail & head) ----------------
__global__ __launch_bounds__(256)
void ln_elu_kernel(const float* __restrict__ in, float* __restrict__ outf,
                   unsigned short* __restrict__ outb,
                   const float* __restrict__ g, const float* __restrict__ bb,
                   int Cn, int do_elu) {
  __shared__ float sdata[4];
  size_t row = blockIdx.x;
  const float* x = in + row * Cn;
  int tid = threadIdx.x;
  float v0 = x[tid];
  float v1 = (Cn == 512) ? x[tid + 256] : 0.f;
  float s = v0 + v1;
  #pragma unroll
  for (int off = 32; off > 0; off >>= 1) s += __shfl_xor(s, off, 64);
  if ((tid & 63) == 0) sdata[tid >> 6] = s;
  __syncthreads();
  float mean = (sdata[0] + sdata[1] + sdata[2] + sdata[3]) / (float)Cn;
  float d0 = v0 - mean;
  float d1 = (Cn == 512) ? (v1 - mean) : 0.f;
  float sq = d0 * d0 + d1 * d1;
  __syncthreads();
  #pragma unroll
  for (int off = 32; off > 0; off >>= 1) sq += __shfl_xor(sq, off, 64);
  if ((tid & 63) == 0) sdata[tid >> 6] = sq;
  __syncthreads();
  float var = (sdata[0] + sdata[1] + sdata[2] + sdata[3]) / (float)Cn;
  float r = rsqrtf(var + 1e-5f);
  float y0 = d0 * r * g[tid] + bb[tid];
  if (do_elu) y0 = elu(y0);
  if (outf) outf[row * Cn + tid] = y0;
  if (outb) outb[row * Cn + tid] = f2bf_fast(y0);
  if (Cn == 512) {
    float y1 = d1 * r * g[tid + 256] + bb[tid + 256];
    if (do_elu) y1 = elu(y1);
    if (outf) outf[row * Cn + tid + 256] = y1;
    if (outb) outb[row * Cn + tid + 256] = f2bf_fast(y1);
  }
}

// ---------------- per-channel softmax over K + weighted aggregation ----------------
__global__ __launch_bounds__(256)
void softmax_agg(const unsigned short* __restrict__ alpha_b,
                 const unsigned short* __restrict__ delta_b,
                 const unsigned short* __restrict__ qkv,
                 const int* __restrict__ neigh,
                 float* __restrict__ agg, int node0) {
  int nl = blockIdx.x;
  int c = threadIdx.x;
  int i = node0 + nl;
  float av[KNN];
  float mx = -3.4e38f;
  #pragma unroll
  for (int k = 0; k < KNN; ++k) {
    av[k] = bf2f(alpha_b[((size_t)nl * KNN + k) * HDIM + c]);
    mx = fmaxf(mx, av[k]);
  }
  float ssum = 0.f;
  #pragma unroll
  for (int k = 0; k < KNN; ++k) { av[k] = __expf(av[k] - mx); ssum += av[k]; }
  float inv = 1.f / ssum;
  float acc = 0.f;
  #pragma unroll
  for (int k = 0; k < KNN; ++k) {
    int j = neigh[(size_t)i * KNN + k];
    acc += av[k] * inv * (bf2f(qkv[(size_t)j * QS + 512 + c]) +
                          bf2f(delta_b[((size_t)nl * KNN + k) * HDIM + c]));
  }
  agg[(size_t)i * HDIM + c] = acc;
}

// ---------------- x += res_alpha[l] * h ; xb = bf16(x) ----------------
__global__ __launch_bounds__(256)
void axpy_res(float* __restrict__ x, unsigned short* __restrict__ xb,
              const float* __restrict__ h, const float* __restrict__ alpha, int l) {
  size_t idx = (size_t)blockIdx.x * 256 + threadIdx.x;
  float nv = x[idx] + alpha[l] * h[idx];
  x[idx] = nv;
  xb[idx] = f2bf_fast(nv);
}

// ---------------- global max pool, two-stage ----------------
__global__ __launch_bounds__(256)
void seg_max_p(const float* __restrict__ h, float* __restrict__ part) {
  int blk = blockIdx.x;
  int b = blk >> 4, ch = blk & 15;
  int c = threadIdx.x;
  const float* base = h + ((size_t)b * PPC + (size_t)ch * 64) * HDIM;
  float m = -3.4e38f;
  for (int p = 0; p < 64; ++p)
    m = fmaxf(m, base[(size_t)p * HDIM + c]);
  part[(size_t)blk * HDIM + c] = m;
}
__global__ __launch_bounds__(256)
void seg_max_f(const float* __restrict__ part, float* __restrict__ pooled) {
  int b = blockIdx.x;
  int c = threadIdx.x;
  float m = -3.4e38f;
  for (int k = 0; k < 16; ++k)
    m = fmaxf(m, part[(size_t)(b * 16 + k) * HDIM + c]);
  pooled[(size_t)b * HDIM + c] = m;
}

extern "C" void kernel_launch(void* const* d_in, const int* in_sizes, int n_in,
                              void* d_out, int out_size, void* d_ws, size_t ws_size,
                              hipStream_t stream) {
  const float* pos       = (const float*)d_in[0];
  const float* ffm_W     = (const float*)d_in[2];
  const float* ffm_b     = (const float*)d_in[3];
  const float* lin_W     = (const float*)d_in[4];
  const float* src_W     = (const float*)d_in[5];
  const float* dst_W     = (const float*)d_in[6];
  const float* pos1_W    = (const float*)d_in[7];
  const float* pos1_b    = (const float*)d_in[8];
  const float* pos_ln1_g = (const float*)d_in[9];
  const float* pos_ln1_b = (const float*)d_in[10];
  const float* pos2_W    = (const float*)d_in[11];
  const float* pos2_b    = (const float*)d_in[12];
  const float* pos_ln2_g = (const float*)d_in[13];
  const float* pos_ln2_b = (const float*)d_in[14];
  const float* att1_W    = (const float*)d_in[15];
  const float* att1_b    = (const float*)d_in[16];
  const float* att_ln1_g = (const float*)d_in[17];
  const float* att_ln1_b = (const float*)d_in[18];
  const float* att2_W    = (const float*)d_in[19];
  const float* att2_b    = (const float*)d_in[20];
  const float* att_ln2_g = (const float*)d_in[21];
  const float* att_ln2_b = (const float*)d_in[22];
  const float* blk_ln_g  = (const float*)d_in[23];
  const float* blk_ln_b  = (const float*)d_in[24];
  const float* blk_W     = (const float*)d_in[25];
  const float* blk_b     = (const float*)d_in[26];
  const float* res_alpha = (const float*)d_in[27];
  const float* r1_W = (const float*)d_in[28]; const float* r1_b = (const float*)d_in[29];
  const float* r2_W = (const float*)d_in[30]; const float* r2_b = (const float*)d_in[31];
  const float* r2_ln_g = (const float*)d_in[32]; const float* r2_ln_b = (const float*)d_in[33];
  const float* r3_W = (const float*)d_in[34]; const float* r3_b = (const float*)d_in[35];
  const float* r3_ln_g = (const float*)d_in[36]; const float* r3_ln_b = (const float*)d_in[37];
  const float* r4_W = (const float*)d_in[38]; const float* r4_b = (const float*)d_in[39];
  float* out = (float*)d_out;

  // ---- workspace carve-up ----
  char* wsp = (char*)d_ws;
  auto alloc = [&](size_t bytes) -> void* {
    void* p = (void*)wsp;
    wsp += (bytes + 255) & ~(size_t)255;
    return p;
  };
  int*            neigh   = (int*)alloc(EDG * sizeof(int));
  float*          rel_f   = (float*)alloc((size_t)EDG * 3 * 4);
  unsigned short* posb    = (unsigned short*)alloc((size_t)NPTS * 32 * 2);
  float*          x       = (float*)alloc((size_t)NPTS * HDIM * 4);
  unsigned short* xb      = (unsigned short*)alloc((size_t)NPTS * HDIM * 2);
  unsigned short* xln_b   = (unsigned short*)alloc((size_t)NPTS * HDIM * 2);
  unsigned short* qkv     = (unsigned short*)alloc((size_t)NPTS * QS * 2);
  float*          agg     = (float*)alloc((size_t)NPTS * HDIM * 4);
  float*          segp    = (float*)alloc((size_t)128 * HDIM * 4);
  float*          pooled  = (float*)alloc((size_t)BCL * HDIM * 4);
  float*          hh      = (float*)alloc((size_t)BCL * HDIM * 4);
  unsigned short* ffmt = (unsigned short*)alloc((size_t)HDIM * 32 * 2);
  unsigned short* r1t  = (unsigned short*)alloc((size_t)HDIM * HDIM * 2);
  unsigned short *qkvt[NL], *blkt[NL];
  unsigned short *pos2p[NL], *att1p[NL], *att2p[NL];
  for (int l = 0; l < NL; ++l) {
    qkvt[l]  = (unsigned short*)alloc((size_t)QS * HDIM * 2);
    blkt[l]  = (unsigned short*)alloc((size_t)HDIM * HDIM * 2);
    pos2p[l] = (unsigned short*)alloc((size_t)HDIM * HD2 * 2);   // packed
    att1p[l] = (unsigned short*)alloc((size_t)HD2 * HDIM * 2);   // packed
    att2p[l] = (unsigned short*)alloc((size_t)HDIM * HD2 * 2);   // packed
  }
  // chunked edge buffers: delta + alpha (bf16)
  size_t used = (size_t)(wsp - (char*)d_ws);
  size_t avail = (ws_size > used) ? (ws_size - used) : 0;
  size_t per_node = (size_t)KNN * (HDIM * 2 * 2) + 1024;
  int Nc = (int)(avail / per_node);
  if (Nc > NPTS) Nc = NPTS;
  Nc &= ~15;
  if (Nc < 16) Nc = 16;
  unsigned short* delta_b = (unsigned short*)alloc((size_t)Nc * KNN * HDIM * 2);
  unsigned short* alpha_b = (unsigned short*)alloc((size_t)Nc * KNN * HDIM * 2);

  auto mgemm = [&](const unsigned short* A, const unsigned short* Bt, const float* bias,
                   float* Cf, unsigned short* Cb, int M, int Nn, int Kk) {
    dim3 g(Nn / 128, (M + 127) / 128);
    gemm_mfma<<<g, dim3(256), 0, stream>>>(A, Bt, bias, Cf, Cb, M, Nn, Kk);
  };
  auto fgemm = [&](const float* A, const float* Bw, const float* bias, float* Cp,
                   int M, int Nn, int Kk) {
    dim3 g((Nn + BN0 - 1) / BN0, (M + BM0 - 1) / BM0);
    gemm_bias<<<g, dim3(256), 0, stream>>>(A, Bw, bias, Cp, M, Nn, Kk);
  };

  // ---- weight prep ----
  transpose_w<<<HDIM, 256, 0, stream>>>(ffm_W, ffmt, 3, HDIM, 32);
  transpose_w<<<HDIM, 256, 0, stream>>>(r1_W, r1t, HDIM, HDIM, HDIM);
  for (int l = 0; l < NL; ++l) {
    transpose_w<<<HDIM, 256, 0, stream>>>(src_W + (size_t)l * HDIM * HDIM, qkvt[l], HDIM, HDIM, HDIM);
    transpose_w<<<HDIM, 256, 0, stream>>>(dst_W + (size_t)l * HDIM * HDIM, qkvt[l] + 256 * 256, HDIM, HDIM, HDIM);
    transpose_w<<<HDIM, 256, 0, stream>>>(lin_W + (size_t)l * HDIM * HDIM, qkvt[l] + 512 * 256, HDIM, HDIM, HDIM);
    transpose_w<<<HDIM, 256, 0, stream>>>(blk_W + (size_t)l * HDIM * HDIM, blkt[l], HDIM, HDIM, HDIM);
    pack_w<<<(HD2 / 32) * (HDIM / 16), 64, 0, stream>>>(pos2_W + (size_t)l * HD2 * HDIM, pos2p[l], HDIM);
    pack_w<<<(HDIM / 32) * (HD2 / 16), 64, 0, stream>>>(att1_W + (size_t)l * HDIM * HD2, att1p[l], HD2);
    pack_w<<<(HD2 / 32) * (HDIM / 16), 64, 0, stream>>>(att2_W + (size_t)l * HD2 * HDIM, att2p[l], HDIM);
  }

  // ---- graph + stem ----
  knn_wave<<<NPTS / 4, 256, 0, stream>>>(pos, neigh, rel_f);
  prep_pos<<<NPTS * 32 / 256, 256, 0, stream>>>(pos, posb);
  mgemm(posb, ffmt, ffm_b, x, xb, NPTS, HDIM, 32);

  // ---- transformer layers ----
  for (int l = 0; l < NL; ++l) {
    mgemm(xb, qkvt[l], nullptr, nullptr, qkv, NPTS, QS, HDIM);   // [a_src|a_dst|v]

    for (int n0 = 0; n0 < NPTS; n0 += Nc) {
      int nc = (Nc < NPTS - n0) ? Nc : (NPTS - n0);
      int ec = nc * KNN;
      pos_fused<<<ec / 32, 256, 0, stream>>>(
          rel_f, pos1_W + (size_t)l * 3 * HD2, pos1_b + (size_t)l * HD2,
          pos_ln1_g + (size_t)l * HD2, pos_ln1_b + (size_t)l * HD2,
          pos2p[l], pos2_b + (size_t)l * HDIM,
          pos_ln2_g + (size_t)l * HDIM, pos_ln2_b + (size_t)l * HDIM,
          delta_b, n0 * KNN);
      attn_fused<<<ec / 32, 256, 0, stream>>>(
          qkv, delta_b, neigh,
          att1p[l], att1_b + (size_t)l * HD2,
          att_ln1_g + (size_t)l * HD2, att_ln1_b + (size_t)l * HD2,
          att2p[l], att2_b + (size_t)l * HDIM,
          att_ln2_g + (size_t)l * HDIM, att_ln2_b + (size_t)l * HDIM,
          alpha_b, n0 * KNN);
      softmax_agg<<<nc, 256, 0, stream>>>(alpha_b, delta_b, qkv, neigh, agg, n0);
    }
    ln_elu_kernel<<<NPTS, 256, 0, stream>>>(agg, nullptr, xln_b,
                                            blk_ln_g + (size_t)l * HDIM, blk_ln_b + (size_t)l * HDIM, HDIM, 1);
    mgemm(xln_b, blkt[l], blk_b + (size_t)l * HDIM, agg, nullptr, NPTS, HDIM, HDIM);
    axpy_res<<<(NPTS * HDIM) / 256, 256, 0, stream>>>(x, xb, agg, res_alpha, l);
  }

  // ---- regression head ----
  mgemm(xb, r1t, r1_b, agg, nullptr, NPTS, HDIM, HDIM);
  seg_max_p<<<128, 256, 0, stream>>>(agg, segp);
  seg_max_f<<<BCL, 256, 0, stream>>>(segp, pooled);
  fgemm(pooled, r2_W, r2_b, hh, BCL, HDIM, HDIM);
  ln_elu_kernel<<<BCL, 256, 0, stream>>>(hh, hh, nullptr, r2_ln_g, r2_ln_b, HDIM, 1);
  fgemm(hh, r3_W, r3_b, pooled, BCL, HDIM, HDIM);
  ln_elu_kernel<<<BCL, 256, 0, stream>>>(pooled, pooled, nullptr, r3_ln_g, r3_ln_b, HDIM, 1);
  fgemm(pooled, r4_W, r4_b, out, BCL, NCOMP, HDIM);
}